// Round 1
// baseline (1147.149 us; speedup 1.0000x reference)
//
#include <hip/hip_runtime.h>

#define T_ 7
#define H_ 48
#define W_ 48
#define C_ 64
#define P_ 16128      // T_*H_*W_
#define HW_ 2304
#define OCOFF 54

// ---------- transpose [C][P] -> [P][C] ----------
__global__ void k_tr_fw(const float* __restrict__ in, float* __restrict__ out) {
  __shared__ float tile[64][65];
  int p0 = blockIdx.x * 64;
  int l = threadIdx.x & 63;
  int g = threadIdx.x >> 6;       // 0..3
#pragma unroll
  for (int i = 0; i < 16; ++i) {
    int c = g * 16 + i;
    tile[c][l] = in[c * P_ + p0 + l];
  }
  __syncthreads();
#pragma unroll
  for (int i = 0; i < 16; ++i) {
    int p = g * 16 + i;
    out[(p0 + p) * 64 + l] = tile[l][p];
  }
}

// ---------- transpose [P][C] -> [C][P] ----------
__global__ void k_tr_bk(const float* __restrict__ in, float* __restrict__ out) {
  __shared__ float tile[64][65];
  int p0 = blockIdx.x * 64;
  int l = threadIdx.x & 63;
  int g = threadIdx.x >> 6;
#pragma unroll
  for (int i = 0; i < 16; ++i) {
    int p = g * 16 + i;
    tile[l][p] = in[(p0 + p) * 64 + l];
  }
  __syncthreads();
#pragma unroll
  for (int i = 0; i < 16; ++i) {
    int c = g * 16 + i;
    out[c * P_ + p0 + l] = tile[c][l];
  }
}

// ---------- weight transpose: w[o][c][k] -> wt[k][c][o] ----------
__global__ void k_wt_tr(const float* __restrict__ w, float* __restrict__ wt) {
  int idx = blockIdx.x * 256 + threadIdx.x;   // < 27*64*64 = 110592
  int o = idx & 63;
  int c = (idx >> 6) & 63;
  int k = idx >> 12;
  wt[idx] = w[(o * 64 + c) * 27 + k];
}

// ---------- 3x3x3 conv, 64 -> 54 channels (offset prediction) ----------
// in: [64][T][H][W], wt: [54][64][27], out: [54][P]
__global__ void k_conv_off(const float* __restrict__ x, const float* __restrict__ wt,
                           const float* __restrict__ bias, float* __restrict__ out) {
  int idx = blockIdx.x * 256 + threadIdx.x;   // < 54*16128 = 870912
  int p = idx % P_;
  int oc = idx / P_;
  int t = p / HW_;
  int r = p % HW_;
  int h = r / W_;
  int w = r % W_;
  float acc = bias[oc];
  for (int kt = 0; kt < 3; ++kt) {
    int t2 = t + kt - 1;
    if (t2 < 0 || t2 >= T_) continue;
    for (int kh = 0; kh < 3; ++kh) {
      int h2 = h + kh - 1;
      if (h2 < 0 || h2 >= H_) continue;
      const float* xr = x + (t2 * H_ + h2) * W_;
      const float* wr = wt + oc * 1728 + kt * 9 + kh * 3;  // + c*27 + kw
      for (int c = 0; c < 64; ++c) {
        const float* xc = xr + c * P_;
        float w0v = wr[c * 27 + 0];
        float w1v = wr[c * 27 + 1];
        float w2v = wr[c * 27 + 2];
        float xm  = (w > 0)      ? xc[w - 1] : 0.f;
        float x0  = xc[w];
        float xp2 = (w < W_ - 1) ? xc[w + 1] : 0.f;
        acc += xm * w0v + x0 * w1v + xp2 * w2v;
      }
    }
  }
  out[idx] = acc;
}

// ---------- deformable sample + 64x64x27 conv ----------
// xcl: [P][64] (channels-last sampling source)
// off: [54][P]  (channel = k*2 + d, d=0 -> h offset, d=1 -> w offset)
// wt:  [27][64][64]  ([k][c][o])
// MODE 0: out = leaky_relu(acc + bias)      (resid unused)
// MODE 1: out = acc + bias + resid[p][o]
template <int MODE>
__global__ void k_sample_conv(const float* __restrict__ xcl, const float* __restrict__ off,
                              const float* __restrict__ wt, const float* __restrict__ bias,
                              const float* __restrict__ resid, float* __restrict__ outcl) {
  int p = blockIdx.x;
  int t = p / HW_;
  int r = p % HW_;
  int h = r / W_;
  int w = r % W_;
  int lane = threadIdx.x;   // 0..63
  __shared__ float vbuf[64];
  float acc = 0.f;
  for (int k = 0; k < 27; ++k) {
    int kt = k / 9;
    int t2 = t + kt - 1;
    if (t2 < 0 || t2 >= T_) continue;   // uniform across block: sample contributes 0
    int kh = (k / 3) % 3;
    int kw = k % 3;
    float oh = off[(2 * k + 0) * P_ + p];
    float ow = off[(2 * k + 1) * P_ + p];
    float ph = (float)(h + kh - 1) + oh;
    float pw = (float)(w + kw - 1) + ow;
    float h0f = floorf(ph), w0f = floorf(pw);
    float lh = ph - h0f, lw = pw - w0f;
    int h0 = (int)h0f, w0 = (int)w0f;
    int h1 = h0 + 1, w1 = w0 + 1;
    bool hok0 = (h0 >= 0) && (h0 < H_);
    bool hok1 = (h1 >= 0) && (h1 < H_);
    bool wok0 = (w0 >= 0) && (w0 < W_);
    bool wok1 = (w1 >= 0) && (w1 < W_);
    int hc0 = min(max(h0, 0), H_ - 1), hc1 = min(max(h1, 0), H_ - 1);
    int wc0 = min(max(w0, 0), W_ - 1), wc1 = min(max(w1, 0), W_ - 1);
    const float* base = xcl + (size_t)(t2 * HW_) * 64;
    float v00 = base[(hc0 * W_ + wc0) * 64 + lane];
    float v01 = base[(hc0 * W_ + wc1) * 64 + lane];
    float v10 = base[(hc1 * W_ + wc0) * 64 + lane];
    float v11 = base[(hc1 * W_ + wc1) * 64 + lane];
    float g00 = (hok0 && wok0) ? (1.f - lh) * (1.f - lw) : 0.f;
    float g01 = (hok0 && wok1) ? (1.f - lh) * lw : 0.f;
    float g10 = (hok1 && wok0) ? lh * (1.f - lw) : 0.f;
    float g11 = (hok1 && wok1) ? lh * lw : 0.f;
    float v = g00 * v00 + g01 * v01 + g10 * v10 + g11 * v11;
    __syncthreads();
    vbuf[lane] = v;
    __syncthreads();
    const float4* vb4 = (const float4*)vbuf;
    const float* wk = wt + k * 4096 + lane;   // + c*64
#pragma unroll
    for (int c4 = 0; c4 < 16; ++c4) {
      float4 vv = vb4[c4];
      acc += vv.x * wk[(c4 * 4 + 0) * 64];
      acc += vv.y * wk[(c4 * 4 + 1) * 64];
      acc += vv.z * wk[(c4 * 4 + 2) * 64];
      acc += vv.w * wk[(c4 * 4 + 3) * 64];
    }
  }
  acc += bias[lane];
  if (MODE == 0) {
    acc = (acc >= 0.f) ? acc : 0.1f * acc;
  } else {
    acc += resid[p * 64 + lane];
  }
  outcl[p * 64 + lane] = acc;
}

extern "C" void kernel_launch(void* const* d_in, const int* in_sizes, int n_in,
                              void* d_out, int out_size, void* d_ws, size_t ws_size,
                              hipStream_t stream) {
  const float* x      = (const float*)d_in[0];
  const float* w_off0 = (const float*)d_in[1];
  const float* b_off0 = (const float*)d_in[2];
  const float* w0     = (const float*)d_in[3];
  const float* b0     = (const float*)d_in[4];
  const float* w_off1 = (const float*)d_in[5];
  const float* b_off1 = (const float*)d_in[6];
  const float* w1     = (const float*)d_in[7];
  const float* b1     = (const float*)d_in[8];
  float* out = (float*)d_out;

  float* ws      = (float*)d_ws;
  float* x_cl    = ws;                   // 1032192
  float* off_buf = x_cl + 1032192;       // 870912  (reused for both layers)
  float* h_cl    = off_buf + 870912;     // 1032192
  float* buf2    = h_cl + 1032192;       // 1032192 (h_cthw, then out_cl)
  float* w0t     = buf2 + 1032192;       // 110592
  float* w1t     = w0t + 110592;         // 110592

  hipLaunchKernelGGL(k_tr_fw, dim3(252), dim3(256), 0, stream, x, x_cl);
  hipLaunchKernelGGL(k_wt_tr, dim3(432), dim3(256), 0, stream, w0, w0t);
  hipLaunchKernelGGL(k_wt_tr, dim3(432), dim3(256), 0, stream, w1, w1t);

  // layer 0
  hipLaunchKernelGGL(k_conv_off, dim3(3402), dim3(256), 0, stream, x, w_off0, b_off0, off_buf);
  hipLaunchKernelGGL((k_sample_conv<0>), dim3(16128), dim3(64), 0, stream,
                     x_cl, off_buf, w0t, b0, (const float*)nullptr, h_cl);
  hipLaunchKernelGGL(k_tr_bk, dim3(252), dim3(256), 0, stream, h_cl, buf2);

  // layer 1
  hipLaunchKernelGGL(k_conv_off, dim3(3402), dim3(256), 0, stream, buf2, w_off1, b_off1, off_buf);
  hipLaunchKernelGGL((k_sample_conv<1>), dim3(16128), dim3(64), 0, stream,
                     h_cl, off_buf, w1t, b1, x_cl, buf2);
  hipLaunchKernelGGL(k_tr_bk, dim3(252), dim3(256), 0, stream, buf2, out);
}

// Round 2
// 216.927 us; speedup vs baseline: 5.2882x; 5.2882x over previous
//
#include <hip/hip_runtime.h>

#define T_ 7
#define H_ 48
#define W_ 48
#define P_ 16128      // T_*H_*W_
#define HW_ 2304

typedef __attribute__((ext_vector_type(8))) short short8;
typedef __attribute__((ext_vector_type(4))) float f32x4;

__device__ __forceinline__ unsigned short f2bf(float f) {
  union { float f; unsigned u; } x{f};
  unsigned r = x.u + 0x7FFFu + ((x.u >> 16) & 1u);
  return (unsigned short)(r >> 16);
}
__device__ __forceinline__ unsigned pack2(float a, float b) {
  return (unsigned)f2bf(a) | ((unsigned)f2bf(b) << 16);
}

// ---------- x [64][P] fp32 -> x_cl [P][64] fp32 + x_clb [P][64] bf16 ----------
__global__ void k_prep_x(const float* __restrict__ in, float* __restrict__ out,
                         unsigned short* __restrict__ outb) {
  __shared__ float tile[64][65];
  int p0 = blockIdx.x * 64;
  int l = threadIdx.x & 63;
  int g = threadIdx.x >> 6;
#pragma unroll
  for (int i = 0; i < 16; ++i) {
    int c = g * 16 + i;
    tile[c][l] = in[c * P_ + p0 + l];
  }
  __syncthreads();
#pragma unroll
  for (int i = 0; i < 16; ++i) {
    int p = g * 16 + i;
    float v = tile[l][p];
    out[(p0 + p) * 64 + l] = v;
    outb[(p0 + p) * 64 + l] = f2bf(v);
  }
}

// ---------- [P][64] fp32 -> [64][P] fp32 ----------
__global__ void k_tr_bk(const float* __restrict__ in, float* __restrict__ out) {
  __shared__ float tile[64][65];
  int p0 = blockIdx.x * 64;
  int l = threadIdx.x & 63;
  int g = threadIdx.x >> 6;
#pragma unroll
  for (int i = 0; i < 16; ++i) {
    int p = g * 16 + i;
    tile[l][p] = in[(p0 + p) * 64 + l];
  }
  __syncthreads();
#pragma unroll
  for (int i = 0; i < 16; ++i) {
    int c = g * 16 + i;
    out[c * P_ + p0 + l] = tile[c][l];
  }
}

// ---------- w_off [54][64][27] -> wA [27][64oc(pad)][64c] bf16 ----------
__global__ void k_prep_wA(const float* __restrict__ w, unsigned short* __restrict__ wA) {
  int idx = blockIdx.x * 256 + threadIdx.x;   // < 110592
  int c = idx & 63;
  int oc = (idx >> 6) & 63;
  int k = idx >> 12;
  wA[idx] = (oc < 54) ? f2bf(w[(oc * 64 + c) * 27 + k]) : (unsigned short)0;
}

// ---------- w [64][64][27] -> wB [27][64o][64c] bf16 ----------
__global__ void k_prep_wB(const float* __restrict__ w, unsigned short* __restrict__ wB) {
  int idx = blockIdx.x * 256 + threadIdx.x;   // < 110592
  int c = idx & 63;
  int o = (idx >> 6) & 63;
  int k = idx >> 12;
  wB[idx] = f2bf(w[(o * 64 + c) * 27 + k]);
}

// ---------- offset conv via MFMA: out[oc][p] ----------
// xclb: [P][64] bf16 channels-last; wA: [27][64][64]; off: [54][P] fp32
__global__ void k_off_mfma(const unsigned short* __restrict__ xclb,
                           const unsigned short* __restrict__ wA,
                           const float* __restrict__ boff, float* __restrict__ off) {
  __shared__ unsigned short bx[50 * 72];
  int blk = blockIdx.x;            // t*48 + h
  int t = blk / 48, h = blk % 48;
  int rowbase = t * HW_ + h * W_;
  int tid = threadIdx.x;
  int lane = tid & 63, wid = tid >> 6;
  int ln = lane & 15, hi = lane >> 4;

  if (tid < 18) {                   // zero pad rows 0 and 49 (once)
    int row = (tid < 9) ? 0 : 49;
    int cc = (tid % 9) * 8;
    *(uint4*)&bx[row * 72 + cc] = uint4{0, 0, 0, 0};
  }
  f32x4 acc[3];
#pragma unroll
  for (int nt = 0; nt < 3; ++nt) acc[nt] = f32x4{0.f, 0.f, 0.f, 0.f};

  for (int kt = 0; kt < 3; ++kt) {
    int t2 = t + kt - 1;
    for (int kh = 0; kh < 3; ++kh) {
      int h2 = h + kh - 1;
      bool valid = (t2 >= 0) && (t2 < T_) && (h2 >= 0) && (h2 < H_);
      __syncthreads();
      if (valid) {
        const unsigned short* src = xclb + (size_t)(t2 * HW_ + h2 * W_) * 64;
        for (int ch = tid; ch < 384; ch += 256) {
          int w = ch >> 3, cc = (ch & 7) * 8;
          *(uint4*)&bx[(w + 1) * 72 + cc] = *(const uint4*)&src[w * 64 + cc];
        }
      }
      __syncthreads();
      if (!valid) continue;
#pragma unroll
      for (int kw = 0; kw < 3; ++kw) {
        int tap = kt * 9 + kh * 3 + kw;
#pragma unroll
        for (int kc = 0; kc < 2; ++kc) {
          short8 a = *(const short8*)&wA[((size_t)tap * 64 + wid * 16 + ln) * 64 + kc * 32 + hi * 8];
#pragma unroll
          for (int nt = 0; nt < 3; ++nt) {
            short8 b = *(const short8*)&bx[(nt * 16 + ln + kw) * 72 + kc * 32 + hi * 8];
            acc[nt] = __builtin_amdgcn_mfma_f32_16x16x32_bf16(a, b, acc[nt], 0, 0, 0);
          }
        }
      }
    }
  }
  int oc_base = wid * 16 + hi * 4;
#pragma unroll
  for (int nt = 0; nt < 3; ++nt) {
#pragma unroll
    for (int r = 0; r < 4; ++r) {
      int oc = oc_base + r;
      if (oc < 54) off[(size_t)oc * P_ + rowbase + nt * 16 + ln] = acc[nt][r] + boff[oc];
    }
  }
}

// ---------- deformable sample + MFMA conv ----------
// xs: [P][64] fp32 sampling source; off: [54][P]; wB: [27][64o][64c] bf16
// MODE 0: leaky -> out_cl fp32 + out_clb bf16.  MODE 1: + resid -> out_cl fp32.
template <int MODE>
__global__ void k_samp_mfma(const float* __restrict__ xs, const float* __restrict__ off,
                            const unsigned short* __restrict__ wB,
                            const float* __restrict__ bias, const float* __restrict__ resid,
                            float* __restrict__ out_cl, unsigned short* __restrict__ out_clb) {
  __shared__ unsigned short sA[48 * 72];
  int blk = blockIdx.x;
  int t = blk / 48, h = blk % 48;
  int rowbase = t * HW_ + h * W_;
  int tid = threadIdx.x;
  int lane = tid & 63, wid = tid >> 6;
  int ln = lane & 15, hi = lane >> 4;
  int sp = tid % 48;            // sampling point (tid < 192)
  int c0 = (tid / 48) * 16;     // channel group
  bool samp_act = tid < 192;

  f32x4 acc[3];
#pragma unroll
  for (int mt = 0; mt < 3; ++mt) acc[mt] = f32x4{0.f, 0.f, 0.f, 0.f};

  for (int kt = 0; kt < 3; ++kt) {
    int t2 = t + kt - 1;
    if (t2 < 0 || t2 >= T_) continue;   // uniform: taps contribute 0
    const float* base = xs + (size_t)t2 * HW_ * 64;
    for (int khw = 0; khw < 9; ++khw) {
      int kh = khw / 3, kw = khw % 3;
      int tap = kt * 9 + khw;
      __syncthreads();
      if (samp_act) {
        float oh = off[(size_t)(2 * tap) * P_ + rowbase + sp];
        float ow = off[(size_t)(2 * tap + 1) * P_ + rowbase + sp];
        float ph = (float)(h + kh - 1) + oh;
        float pw = (float)(sp + kw - 1) + ow;
        float h0f = floorf(ph), w0f = floorf(pw);
        float lh = ph - h0f, lw = pw - w0f;
        int h0 = (int)h0f, w0 = (int)w0f;
        int h1 = h0 + 1, w1 = w0 + 1;
        bool hok0 = (h0 >= 0) && (h0 < H_);
        bool hok1 = (h1 >= 0) && (h1 < H_);
        bool wok0 = (w0 >= 0) && (w0 < W_);
        bool wok1 = (w1 >= 0) && (w1 < W_);
        int hc0 = min(max(h0, 0), H_ - 1), hc1 = min(max(h1, 0), H_ - 1);
        int wc0 = min(max(w0, 0), W_ - 1), wc1 = min(max(w1, 0), W_ - 1);
        float g00 = (hok0 && wok0) ? (1.f - lh) * (1.f - lw) : 0.f;
        float g01 = (hok0 && wok1) ? (1.f - lh) * lw : 0.f;
        float g10 = (hok1 && wok0) ? lh * (1.f - lw) : 0.f;
        float g11 = (hok1 && wok1) ? lh * lw : 0.f;
        const float4* p00 = (const float4*)(base + ((hc0 * W_ + wc0) * 64 + c0));
        const float4* p01 = (const float4*)(base + ((hc0 * W_ + wc1) * 64 + c0));
        const float4* p10 = (const float4*)(base + ((hc1 * W_ + wc0) * 64 + c0));
        const float4* p11 = (const float4*)(base + ((hc1 * W_ + wc1) * 64 + c0));
        unsigned u[8];
#pragma unroll
        for (int q = 0; q < 4; ++q) {
          float4 v00 = p00[q], v01 = p01[q], v10 = p10[q], v11 = p11[q];
          float vx = g00 * v00.x + g01 * v01.x + g10 * v10.x + g11 * v11.x;
          float vy = g00 * v00.y + g01 * v01.y + g10 * v10.y + g11 * v11.y;
          float vz = g00 * v00.z + g01 * v01.z + g10 * v10.z + g11 * v11.z;
          float vw = g00 * v00.w + g01 * v01.w + g10 * v10.w + g11 * v11.w;
          u[q * 2] = pack2(vx, vy);
          u[q * 2 + 1] = pack2(vz, vw);
        }
        *(uint4*)&sA[sp * 72 + c0] = uint4{u[0], u[1], u[2], u[3]};
        *(uint4*)&sA[sp * 72 + c0 + 8] = uint4{u[4], u[5], u[6], u[7]};
      }
      __syncthreads();
#pragma unroll
      for (int kc = 0; kc < 2; ++kc) {
        short8 b = *(const short8*)&wB[((size_t)tap * 64 + wid * 16 + ln) * 64 + kc * 32 + hi * 8];
#pragma unroll
        for (int mt = 0; mt < 3; ++mt) {
          short8 a = *(const short8*)&sA[(mt * 16 + ln) * 72 + kc * 32 + hi * 8];
          acc[mt] = __builtin_amdgcn_mfma_f32_16x16x32_bf16(a, b, acc[mt], 0, 0, 0);
        }
      }
    }
  }
  int o = wid * 16 + ln;
#pragma unroll
  for (int mt = 0; mt < 3; ++mt) {
#pragma unroll
    for (int r = 0; r < 4; ++r) {
      int p = mt * 16 + hi * 4 + r;
      float v = acc[mt][r] + bias[o];
      size_t gi = (size_t)(rowbase + p) * 64 + o;
      if (MODE == 0) {
        v = (v >= 0.f) ? v : 0.1f * v;
        out_cl[gi] = v;
        out_clb[gi] = f2bf(v);
      } else {
        out_cl[gi] = v + resid[gi];
      }
    }
  }
}

extern "C" void kernel_launch(void* const* d_in, const int* in_sizes, int n_in,
                              void* d_out, int out_size, void* d_ws, size_t ws_size,
                              hipStream_t stream) {
  const float* x      = (const float*)d_in[0];
  const float* w_off0 = (const float*)d_in[1];
  const float* b_off0 = (const float*)d_in[2];
  const float* w0     = (const float*)d_in[3];
  const float* b0     = (const float*)d_in[4];
  const float* w_off1 = (const float*)d_in[5];
  const float* b_off1 = (const float*)d_in[6];
  const float* w1     = (const float*)d_in[7];
  const float* b1     = (const float*)d_in[8];
  float* out = (float*)d_out;

  char* base = (char*)d_ws;
  float*          x_cl  = (float*)base;                           // 4,128,768 B
  float*          h_cl  = (float*)(base + 4128768);               // 4,128,768 B
  float*          o2_cl = (float*)(base + 8257536);               // 4,128,768 B
  float*          offb  = (float*)(base + 12386304);              // 3,483,648 B
  unsigned short* x_clb = (unsigned short*)(base + 15869952);     // 2,064,384 B
  unsigned short* h_clb = (unsigned short*)(base + 17934336);     // 2,064,384 B
  unsigned short* wA0   = (unsigned short*)(base + 19998720);     // 221,184 B
  unsigned short* wA1   = (unsigned short*)(base + 20219904);
  unsigned short* wB0   = (unsigned short*)(base + 20441088);
  unsigned short* wB1   = (unsigned short*)(base + 20662272);     // end ~20.9 MB

  hipLaunchKernelGGL(k_prep_x, dim3(252), dim3(256), 0, stream, x, x_cl, x_clb);
  hipLaunchKernelGGL(k_prep_wA, dim3(432), dim3(256), 0, stream, w_off0, wA0);
  hipLaunchKernelGGL(k_prep_wA, dim3(432), dim3(256), 0, stream, w_off1, wA1);
  hipLaunchKernelGGL(k_prep_wB, dim3(432), dim3(256), 0, stream, w0, wB0);
  hipLaunchKernelGGL(k_prep_wB, dim3(432), dim3(256), 0, stream, w1, wB1);

  // layer 0
  hipLaunchKernelGGL(k_off_mfma, dim3(336), dim3(256), 0, stream, x_clb, wA0, b_off0, offb);
  hipLaunchKernelGGL((k_samp_mfma<0>), dim3(336), dim3(256), 0, stream,
                     x_cl, offb, wB0, b0, (const float*)nullptr, h_cl, h_clb);

  // layer 1
  hipLaunchKernelGGL(k_off_mfma, dim3(336), dim3(256), 0, stream, h_clb, wA1, b_off1, offb);
  hipLaunchKernelGGL((k_samp_mfma<1>), dim3(336), dim3(256), 0, stream,
                     h_cl, offb, wB1, b1, x_cl, o2_cl, (unsigned short*)nullptr);

  hipLaunchKernelGGL(k_tr_bk, dim3(252), dim3(256), 0, stream, o2_cl, out);
}

// Round 3
// 184.153 us; speedup vs baseline: 6.2293x; 1.1780x over previous
//
#include <hip/hip_runtime.h>

#define T_ 7
#define H_ 48
#define W_ 48
#define P_ 16128      // T_*H_*W_
#define HW_ 2304

typedef __attribute__((ext_vector_type(8))) short short8;
typedef __attribute__((ext_vector_type(4))) float f32x4;

__device__ __forceinline__ unsigned short f2bf(float f) {
  union { float f; unsigned u; } x{f};
  unsigned r = x.u + 0x7FFFu + ((x.u >> 16) & 1u);
  return (unsigned short)(r >> 16);
}
__device__ __forceinline__ float blo(unsigned u) {
  union { unsigned u; float f; } x{u << 16};
  return x.f;
}
__device__ __forceinline__ float bhi(unsigned u) {
  union { unsigned u; float f; } x{u & 0xFFFF0000u};
  return x.f;
}
__device__ __forceinline__ unsigned cvtpk(float a, float b) {
  unsigned r;
  asm("v_cvt_pk_bf16_f32 %0, %1, %2" : "=v"(r) : "v"(a), "v"(b));
  return r;
}

// ---------- x [64][P] fp32 -> x_clb [P][64] bf16 ----------
__global__ void k_prep_x(const float* __restrict__ in, unsigned short* __restrict__ outb) {
  __shared__ float tile[64][65];
  int p0 = blockIdx.x * 64;
  int l = threadIdx.x & 63;
  int g = threadIdx.x >> 6;
#pragma unroll
  for (int i = 0; i < 16; ++i) {
    int c = g * 16 + i;
    tile[c][l] = in[c * P_ + p0 + l];
  }
  __syncthreads();
#pragma unroll
  for (int i = 0; i < 16; ++i) {
    int p = g * 16 + i;
    outb[(p0 + p) * 64 + l] = f2bf(tile[l][p]);
  }
}

// ---------- weights [OC][64][27] fp32 -> [27][64(pad)][64] bf16 ----------
__global__ void k_prep_w(const float* __restrict__ w, unsigned short* __restrict__ wt, int OC) {
  int idx = blockIdx.x * 256 + threadIdx.x;   // < 110592
  int c = idx & 63;
  int o = (idx >> 6) & 63;
  int k = idx >> 12;
  wt[idx] = (o < OC) ? f2bf(w[(o * 64 + c) * 27 + k]) : (unsigned short)0;
}

// ---------- offset conv: 1 wave per 16-point tile, no LDS, no barriers ----------
// xclb [P][64] bf16; wA [27][64][64]; out offt [P][56] fp32 (oc 0..53)
__global__ __launch_bounds__(64) void k_off16(const unsigned short* __restrict__ xclb,
                                              const unsigned short* __restrict__ wA,
                                              const float* __restrict__ boff,
                                              float* __restrict__ offt) {
  int p0 = blockIdx.x * 16;
  int t = p0 / HW_;
  int rem = p0 - t * HW_;
  int h = rem / W_;
  int w0 = rem - (rem / W_) * W_;
  int lane = threadIdx.x & 63;
  int pt = lane & 15, grp = lane >> 4;

  f32x4 acc0{0.f, 0.f, 0.f, 0.f}, acc1 = acc0, acc2 = acc0, acc3 = acc0;
  const short8 zero8{0, 0, 0, 0, 0, 0, 0, 0};

#pragma unroll
  for (int k = 0; k < 27; ++k) {
    const int kt = k / 9, kh = (k / 3) % 3, kw = k % 3;
    int t2 = t + kt - 1;
    int h2 = h + kh - 1;
    int w2 = w0 + pt + kw - 1;
    bool ok = ((unsigned)t2 < (unsigned)T_) & ((unsigned)h2 < (unsigned)H_) &
              ((unsigned)w2 < (unsigned)W_);
    int t2c = min(max(t2, 0), T_ - 1);
    int h2c = min(max(h2, 0), H_ - 1);
    int w2c = min(max(w2, 0), W_ - 1);
    const unsigned short* ap = xclb + ((size_t)(t2c * HW_ + h2c * W_ + w2c) * 64 + grp * 8);
    short8 a0 = *(const short8*)ap;
    short8 a1 = *(const short8*)(ap + 32);
    a0 = ok ? a0 : zero8;
    a1 = ok ? a1 : zero8;
    const unsigned short* wp = wA + ((size_t)k * 64 + pt) * 64 + grp * 8;
    short8 b00 = *(const short8*)(wp);
    short8 b01 = *(const short8*)(wp + 32);
    short8 b10 = *(const short8*)(wp + 16 * 64);
    short8 b11 = *(const short8*)(wp + 16 * 64 + 32);
    short8 b20 = *(const short8*)(wp + 32 * 64);
    short8 b21 = *(const short8*)(wp + 32 * 64 + 32);
    short8 b30 = *(const short8*)(wp + 48 * 64);
    short8 b31 = *(const short8*)(wp + 48 * 64 + 32);
    acc0 = __builtin_amdgcn_mfma_f32_16x16x32_bf16(a0, b00, acc0, 0, 0, 0);
    acc0 = __builtin_amdgcn_mfma_f32_16x16x32_bf16(a1, b01, acc0, 0, 0, 0);
    acc1 = __builtin_amdgcn_mfma_f32_16x16x32_bf16(a0, b10, acc1, 0, 0, 0);
    acc1 = __builtin_amdgcn_mfma_f32_16x16x32_bf16(a1, b11, acc1, 0, 0, 0);
    acc2 = __builtin_amdgcn_mfma_f32_16x16x32_bf16(a0, b20, acc2, 0, 0, 0);
    acc2 = __builtin_amdgcn_mfma_f32_16x16x32_bf16(a1, b21, acc2, 0, 0, 0);
    acc3 = __builtin_amdgcn_mfma_f32_16x16x32_bf16(a0, b30, acc3, 0, 0, 0);
    acc3 = __builtin_amdgcn_mfma_f32_16x16x32_bf16(a1, b31, acc3, 0, 0, 0);
  }
  // D mapping: out point = p0 + grp*4 + r, oc = os*16 + pt
#pragma unroll
  for (int r = 0; r < 4; ++r) {
    int prow = (p0 + grp * 4 + r) * 56;
    offt[prow + pt]      = acc0[r] + boff[pt];
    offt[prow + 16 + pt] = acc1[r] + boff[16 + pt];
    offt[prow + 32 + pt] = acc2[r] + boff[32 + pt];
    if (pt < 6) offt[prow + 48 + pt] = acc3[r] + boff[48 + pt];
  }
}

// ---------- deformable sample + conv: 1 wave per 16-point tile ----------
// xclb [P][64] bf16; offt [P][56]; wB [27][64][64] bf16
// MODE 0: leaky -> outb [P][64] bf16.  MODE 1: +bias +resid(x [64][P]) -> out [64][P] f32.
template <int MODE>
__global__ __launch_bounds__(64) void k_samp16(
    const unsigned short* __restrict__ xclb, const float* __restrict__ offt,
    const unsigned short* __restrict__ wB, const float* __restrict__ bias,
    const float* __restrict__ resid, float* __restrict__ out32,
    unsigned short* __restrict__ outb) {
  __shared__ unsigned short sA[2][16][72];
  int p0 = blockIdx.x * 16;
  int t = p0 / HW_;
  int rem = p0 - t * HW_;
  int h = rem / W_;
  int w0 = rem - (rem / W_) * W_;
  int lane = threadIdx.x & 63;
  int pt = lane & 15, grp = lane >> 4;

  f32x4 acc0{0.f, 0.f, 0.f, 0.f}, acc1 = acc0, acc2 = acc0, acc3 = acc0;
  const float* offrow = offt + (size_t)(p0 + pt) * 56;
  float hbase = (float)(h - 1);
  float wbase = (float)(w0 + pt - 1);

#pragma unroll 3
  for (int k = 0; k < 27; ++k) {
    int kt = k / 9;
    int r9 = k - kt * 9;
    int kh = r9 / 3;
    int kw = r9 - (r9 / 3) * 3;
    int t2 = t + kt - 1;
    bool tok = ((unsigned)t2 < (unsigned)T_);
    int t2c = min(max(t2, 0), T_ - 1);

    float2 o2 = *(const float2*)(offrow + 2 * k);
    float ph = hbase + (float)kh + o2.x;
    float pw = wbase + (float)kw + o2.y;
    float hf = floorf(ph), wf = floorf(pw);
    float lh = ph - hf, lw = pw - wf;
    int h0 = (int)hf, w0i = (int)wf;
    int h1 = h0 + 1, w1 = w0i + 1;
    bool h0ok = ((unsigned)h0 < (unsigned)H_), h1ok = ((unsigned)h1 < (unsigned)H_);
    bool w0ok = ((unsigned)w0i < (unsigned)W_), w1ok = ((unsigned)w1 < (unsigned)W_);
    int h0c = min(max(h0, 0), H_ - 1), h1c = min(max(h1, 0), H_ - 1);
    int w0c = min(max(w0i, 0), W_ - 1), w1c = min(max(w1, 0), W_ - 1);
    float omlh = 1.f - lh, omlw = 1.f - lw;
    float g00 = (tok & h0ok & w0ok) ? omlh * omlw : 0.f;
    float g01 = (tok & h0ok & w1ok) ? omlh * lw : 0.f;
    float g10 = (tok & h1ok & w0ok) ? lh * omlw : 0.f;
    float g11 = (tok & h1ok & w1ok) ? lh * lw : 0.f;

    const unsigned short* bt = xclb + (size_t)(t2c * HW_) * 64 + grp * 16;
    const uint4* p00 = (const uint4*)(bt + (h0c * W_ + w0c) * 64);
    const uint4* p01 = (const uint4*)(bt + (h0c * W_ + w1c) * 64);
    const uint4* p10 = (const uint4*)(bt + (h1c * W_ + w0c) * 64);
    const uint4* p11 = (const uint4*)(bt + (h1c * W_ + w1c) * 64);
    uint4 A0 = p00[0], A1 = p00[1];
    uint4 B0 = p01[0], B1 = p01[1];
    uint4 C0 = p10[0], C1 = p10[1];
    uint4 D0 = p11[0], D1 = p11[1];

#define LERPU(a, b, c, d)                                                   \
  cvtpk(g00 * blo(a) + g01 * blo(b) + g10 * blo(c) + g11 * blo(d),          \
        g00 * bhi(a) + g01 * bhi(b) + g10 * bhi(c) + g11 * bhi(d))
    uint4 v0, v1;
    v0.x = LERPU(A0.x, B0.x, C0.x, D0.x);
    v0.y = LERPU(A0.y, B0.y, C0.y, D0.y);
    v0.z = LERPU(A0.z, B0.z, C0.z, D0.z);
    v0.w = LERPU(A0.w, B0.w, C0.w, D0.w);
    v1.x = LERPU(A1.x, B1.x, C1.x, D1.x);
    v1.y = LERPU(A1.y, B1.y, C1.y, D1.y);
    v1.z = LERPU(A1.z, B1.z, C1.z, D1.z);
    v1.w = LERPU(A1.w, B1.w, C1.w, D1.w);
#undef LERPU

    *(uint4*)&sA[k & 1][pt][grp * 16] = v0;
    *(uint4*)&sA[k & 1][pt][grp * 16 + 8] = v1;
    __builtin_amdgcn_wave_barrier();   // keep ds_read after ds_write (same wave, in-order LDS)

    short8 af0 = *(const short8*)&sA[k & 1][pt][grp * 8];
    short8 af1 = *(const short8*)&sA[k & 1][pt][32 + grp * 8];
    const unsigned short* wp = wB + ((size_t)k * 64 + pt) * 64 + grp * 8;
    short8 b00 = *(const short8*)(wp);
    short8 b01 = *(const short8*)(wp + 32);
    short8 b10 = *(const short8*)(wp + 16 * 64);
    short8 b11 = *(const short8*)(wp + 16 * 64 + 32);
    short8 b20 = *(const short8*)(wp + 32 * 64);
    short8 b21 = *(const short8*)(wp + 32 * 64 + 32);
    short8 b30 = *(const short8*)(wp + 48 * 64);
    short8 b31 = *(const short8*)(wp + 48 * 64 + 32);
    acc0 = __builtin_amdgcn_mfma_f32_16x16x32_bf16(af0, b00, acc0, 0, 0, 0);
    acc0 = __builtin_amdgcn_mfma_f32_16x16x32_bf16(af1, b01, acc0, 0, 0, 0);
    acc1 = __builtin_amdgcn_mfma_f32_16x16x32_bf16(af0, b10, acc1, 0, 0, 0);
    acc1 = __builtin_amdgcn_mfma_f32_16x16x32_bf16(af1, b11, acc1, 0, 0, 0);
    acc2 = __builtin_amdgcn_mfma_f32_16x16x32_bf16(af0, b20, acc2, 0, 0, 0);
    acc2 = __builtin_amdgcn_mfma_f32_16x16x32_bf16(af1, b21, acc2, 0, 0, 0);
    acc3 = __builtin_amdgcn_mfma_f32_16x16x32_bf16(af0, b30, acc3, 0, 0, 0);
    acc3 = __builtin_amdgcn_mfma_f32_16x16x32_bf16(af1, b31, acc3, 0, 0, 0);
  }

  // out point = p0 + grp*4 + r; channel = os*16 + pt
  float bb0 = bias[pt], bb1 = bias[16 + pt], bb2 = bias[32 + pt], bb3 = bias[48 + pt];
#pragma unroll
  for (int r = 0; r < 4; ++r) {
    int p = p0 + grp * 4 + r;
    float v0 = acc0[r] + bb0;
    float v1 = acc1[r] + bb1;
    float v2 = acc2[r] + bb2;
    float v3 = acc3[r] + bb3;
    if (MODE == 0) {
      v0 = (v0 >= 0.f) ? v0 : 0.1f * v0;
      v1 = (v1 >= 0.f) ? v1 : 0.1f * v1;
      v2 = (v2 >= 0.f) ? v2 : 0.1f * v2;
      v3 = (v3 >= 0.f) ? v3 : 0.1f * v3;
      outb[(size_t)p * 64 + pt]      = f2bf(v0);
      outb[(size_t)p * 64 + 16 + pt] = f2bf(v1);
      outb[(size_t)p * 64 + 32 + pt] = f2bf(v2);
      outb[(size_t)p * 64 + 48 + pt] = f2bf(v3);
    } else {
      out32[(size_t)(pt) * P_ + p]      = v0 + resid[(size_t)(pt) * P_ + p];
      out32[(size_t)(16 + pt) * P_ + p] = v1 + resid[(size_t)(16 + pt) * P_ + p];
      out32[(size_t)(32 + pt) * P_ + p] = v2 + resid[(size_t)(32 + pt) * P_ + p];
      out32[(size_t)(48 + pt) * P_ + p] = v3 + resid[(size_t)(48 + pt) * P_ + p];
    }
  }
}

extern "C" void kernel_launch(void* const* d_in, const int* in_sizes, int n_in,
                              void* d_out, int out_size, void* d_ws, size_t ws_size,
                              hipStream_t stream) {
  const float* x      = (const float*)d_in[0];
  const float* w_off0 = (const float*)d_in[1];
  const float* b_off0 = (const float*)d_in[2];
  const float* w0     = (const float*)d_in[3];
  const float* b0     = (const float*)d_in[4];
  const float* w_off1 = (const float*)d_in[5];
  const float* b_off1 = (const float*)d_in[6];
  const float* w1     = (const float*)d_in[7];
  const float* b1     = (const float*)d_in[8];
  float* out = (float*)d_out;

  char* base = (char*)d_ws;
  unsigned short* x_clb = (unsigned short*)base;               // 2,064,384 B
  unsigned short* h_clb = (unsigned short*)(base + 2064384);   // 2,064,384 B
  float*          offt  = (float*)(base + 4128768);            // 3,612,672 B
  unsigned short* wA0   = (unsigned short*)(base + 7741440);   // 221,184 B
  unsigned short* wA1   = (unsigned short*)(base + 7962624);
  unsigned short* wB0   = (unsigned short*)(base + 8183808);
  unsigned short* wB1   = (unsigned short*)(base + 8404992);   // end ~8.6 MB

  hipLaunchKernelGGL(k_prep_x, dim3(252), dim3(256), 0, stream, x, x_clb);
  hipLaunchKernelGGL(k_prep_w, dim3(432), dim3(256), 0, stream, w_off0, wA0, 54);
  hipLaunchKernelGGL(k_prep_w, dim3(432), dim3(256), 0, stream, w_off1, wA1, 54);
  hipLaunchKernelGGL(k_prep_w, dim3(432), dim3(256), 0, stream, w0, wB0, 64);
  hipLaunchKernelGGL(k_prep_w, dim3(432), dim3(256), 0, stream, w1, wB1, 64);

  // layer 0
  hipLaunchKernelGGL(k_off16, dim3(1008), dim3(64), 0, stream, x_clb, wA0, b_off0, offt);
  hipLaunchKernelGGL((k_samp16<0>), dim3(1008), dim3(64), 0, stream,
                     x_clb, offt, wB0, b0, (const float*)nullptr, (float*)nullptr, h_clb);

  // layer 1
  hipLaunchKernelGGL(k_off16, dim3(1008), dim3(64), 0, stream, h_clb, wA1, b_off1, offt);
  hipLaunchKernelGGL((k_samp16<1>), dim3(1008), dim3(64), 0, stream,
                     h_clb, offt, wB1, b1, x, out, (unsigned short*)nullptr);
}

// Round 6
// 179.191 us; speedup vs baseline: 6.4018x; 1.0277x over previous
//
#include <hip/hip_runtime.h>

#define T_ 7
#define H_ 48
#define W_ 48
#define P_ 16128      // T_*H_*W_
#define HW_ 2304

typedef __attribute__((ext_vector_type(8))) short short8;
typedef __attribute__((ext_vector_type(4))) float f32x4;
typedef __attribute__((ext_vector_type(4))) unsigned u32x4;

__device__ __forceinline__ unsigned short f2bf(float f) {
  union { float f; unsigned u; } x{f};
  unsigned r = x.u + 0x7FFFu + ((x.u >> 16) & 1u);
  return (unsigned short)(r >> 16);
}
__device__ __forceinline__ float blo(unsigned u) {
  union { unsigned u; float f; } x{u << 16};
  return x.f;
}
__device__ __forceinline__ float bhi(unsigned u) {
  union { unsigned u; float f; } x{u & 0xFFFF0000u};
  return x.f;
}
__device__ __forceinline__ unsigned pack2(float a, float b) {
  return (unsigned)f2bf(a) | ((unsigned)f2bf(b) << 16);
}

// ---------- x [64][P] fp32 -> x_clb [P][64] bf16 ----------
__global__ void k_prep_x(const float* __restrict__ in, unsigned short* __restrict__ outb) {
  __shared__ float tile[64][65];
  int p0 = blockIdx.x * 64;
  int l = threadIdx.x & 63;
  int g = threadIdx.x >> 6;
#pragma unroll
  for (int i = 0; i < 16; ++i) {
    int c = g * 16 + i;
    tile[c][l] = in[c * P_ + p0 + l];
  }
  __syncthreads();
#pragma unroll
  for (int i = 0; i < 16; ++i) {
    int p = g * 16 + i;
    outb[(p0 + p) * 64 + l] = f2bf(tile[l][p]);
  }
}

// ---------- all 4 weights [OC][64][27] fp32 -> [27][64(pad)][64] bf16 ----------
__global__ void k_prep_w4(const float* __restrict__ s0, const float* __restrict__ s1,
                          const float* __restrict__ s2, const float* __restrict__ s3,
                          unsigned short* __restrict__ d0, unsigned short* __restrict__ d1,
                          unsigned short* __restrict__ d2, unsigned short* __restrict__ d3) {
  int y = blockIdx.y;
  const float* w = (y == 0) ? s0 : (y == 1) ? s1 : (y == 2) ? s2 : s3;
  unsigned short* wt = (y == 0) ? d0 : (y == 1) ? d1 : (y == 2) ? d2 : d3;
  int OC = (y < 2) ? 54 : 64;
  int idx = blockIdx.x * 256 + threadIdx.x;   // < 110592
  int c = idx & 63;
  int o = (idx >> 6) & 63;
  int k = idx >> 12;
  wt[idx] = (o < OC) ? f2bf(w[(o * 64 + c) * 27 + k]) : (unsigned short)0;
}

// ---------- offset conv: 4 waves split 27 taps (7/7/7/6+phantom), LDS-reduce ----------
// xclb [P][64] bf16; wA [27][64][64]; out offt [P][56] fp32 (oc 0..53)
__global__ __launch_bounds__(256) void k_off4w(const unsigned short* __restrict__ xclb,
                                               const unsigned short* __restrict__ wA,
                                               const float* __restrict__ boff,
                                               float* __restrict__ offt) {
  __shared__ f32x4 red[4][4][64];
  int p0 = blockIdx.x * 16;
  int t = p0 / HW_;
  int rem = p0 - t * HW_;
  int h = rem / W_;
  int w0 = rem - (rem / W_) * W_;
  int tid = threadIdx.x;
  int lane = tid & 63, wid = tid >> 6;
  int pt = lane & 15, grp = lane >> 4;

  f32x4 acc0{0.f, 0.f, 0.f, 0.f}, acc1 = acc0, acc2 = acc0, acc3 = acc0;
  const short8 zero8{0, 0, 0, 0, 0, 0, 0, 0};
  int kbeg = wid * 7;

#pragma unroll
  for (int kk = 0; kk < 7; ++kk) {
    int kraw = kbeg + kk;                 // 0..27 (27 = phantom, masked)
    int k = min(kraw, 26);                // all addressing uses clamped k
    int kt = k / 9;
    int r9 = k - kt * 9;
    int kh = r9 / 3;
    int kw = r9 - (r9 / 3) * 3;
    int t2 = t + kt - 1;
    int h2 = h + kh - 1;
    int w2 = w0 + pt + kw - 1;
    bool ok = (kraw < 27) & ((unsigned)t2 < (unsigned)T_) &
              ((unsigned)h2 < (unsigned)H_) & ((unsigned)w2 < (unsigned)W_);
    int t2c = min(max(t2, 0), T_ - 1);
    int h2c = min(max(h2, 0), H_ - 1);
    int w2c = min(max(w2, 0), W_ - 1);
    const unsigned short* ap = xclb + ((size_t)(t2c * HW_ + h2c * W_ + w2c) * 64 + grp * 8);
    short8 a0 = *(const short8*)ap;
    short8 a1 = *(const short8*)(ap + 32);
    a0 = ok ? a0 : zero8;
    a1 = ok ? a1 : zero8;
    const unsigned short* wp = wA + ((size_t)k * 64 + pt) * 64 + grp * 8;
    short8 b00 = *(const short8*)(wp);
    short8 b01 = *(const short8*)(wp + 32);
    short8 b10 = *(const short8*)(wp + 16 * 64);
    short8 b11 = *(const short8*)(wp + 16 * 64 + 32);
    short8 b20 = *(const short8*)(wp + 32 * 64);
    short8 b21 = *(const short8*)(wp + 32 * 64 + 32);
    short8 b30 = *(const short8*)(wp + 48 * 64);
    short8 b31 = *(const short8*)(wp + 48 * 64 + 32);
    acc0 = __builtin_amdgcn_mfma_f32_16x16x32_bf16(a0, b00, acc0, 0, 0, 0);
    acc0 = __builtin_amdgcn_mfma_f32_16x16x32_bf16(a1, b01, acc0, 0, 0, 0);
    acc1 = __builtin_amdgcn_mfma_f32_16x16x32_bf16(a0, b10, acc1, 0, 0, 0);
    acc1 = __builtin_amdgcn_mfma_f32_16x16x32_bf16(a1, b11, acc1, 0, 0, 0);
    acc2 = __builtin_amdgcn_mfma_f32_16x16x32_bf16(a0, b20, acc2, 0, 0, 0);
    acc2 = __builtin_amdgcn_mfma_f32_16x16x32_bf16(a1, b21, acc2, 0, 0, 0);
    acc3 = __builtin_amdgcn_mfma_f32_16x16x32_bf16(a0, b30, acc3, 0, 0, 0);
    acc3 = __builtin_amdgcn_mfma_f32_16x16x32_bf16(a1, b31, acc3, 0, 0, 0);
  }

  red[wid][0][lane] = acc0;
  red[wid][1][lane] = acc1;
  red[wid][2][lane] = acc2;
  red[wid][3][lane] = acc3;
  __syncthreads();
  f32x4 s = red[0][wid][lane];
  s = s + red[1][wid][lane];
  s = s + red[2][wid][lane];
  s = s + red[3][wid][lane];

  int oc = wid * 16 + pt;
  if (oc < 54) {
    float bb = boff[oc];
#pragma unroll
    for (int r = 0; r < 4; ++r) {
      offt[(size_t)(p0 + grp * 4 + r) * 56 + oc] = s[r] + bb;
    }
  }
}

// ---------- deformable sample + conv: 4 waves split 27 taps, per-wave LDS staging ----------
// xclb [P][64] bf16; offt [P][56]; wB [27][64][64] bf16
// MODE 0: leaky -> outb [P][64] bf16.  MODE 1: +bias +resid(x [64][P]) -> out [64][P] f32.
template <int MODE>
__global__ __launch_bounds__(256) void k_samp4w(
    const unsigned short* __restrict__ xclb, const float* __restrict__ offt,
    const unsigned short* __restrict__ wB, const float* __restrict__ bias,
    const float* __restrict__ resid, float* __restrict__ out32,
    unsigned short* __restrict__ outb) {
  __shared__ f32x4 red[4][4][64];
  __shared__ unsigned short sA[4][2][16][72];   // per-wave staging, round-3 layout
  int p0 = blockIdx.x * 16;
  int t = p0 / HW_;
  int rem = p0 - t * HW_;
  int h = rem / W_;
  int w0 = rem - (rem / W_) * W_;
  int tid = threadIdx.x;
  int lane = tid & 63, wid = tid >> 6;
  int pt = lane & 15, grp = lane >> 4;

  f32x4 acc0{0.f, 0.f, 0.f, 0.f}, acc1 = acc0, acc2 = acc0, acc3 = acc0;
  const float* offrow = offt + (size_t)(p0 + pt) * 56;
  float hbase = (float)(h - 1);
  float wbase = (float)(w0 + pt - 1);
  int kbeg = wid * 7;

#pragma unroll
  for (int kk = 0; kk < 7; ++kk) {
    int kraw = kbeg + kk;                 // 0..27 (27 = phantom, masked)
    int k = min(kraw, 26);
    int kt = k / 9;
    int r9 = k - kt * 9;
    int kh = r9 / 3;
    int kw = r9 - (r9 / 3) * 3;
    int t2 = t + kt - 1;
    bool tok = (kraw < 27) & ((unsigned)t2 < (unsigned)T_);
    int t2c = min(max(t2, 0), T_ - 1);

    float2 o2 = *(const float2*)(offrow + 2 * k);
    float ph = hbase + (float)kh + o2.x;
    float pw = wbase + (float)kw + o2.y;
    float hf = floorf(ph), wf = floorf(pw);
    float lh = ph - hf, lw = pw - wf;
    int h0 = (int)hf, w0i = (int)wf;
    int h1 = h0 + 1, w1 = w0i + 1;
    bool h0ok = ((unsigned)h0 < (unsigned)H_), h1ok = ((unsigned)h1 < (unsigned)H_);
    bool w0ok = ((unsigned)w0i < (unsigned)W_), w1ok = ((unsigned)w1 < (unsigned)W_);
    int h0c = min(max(h0, 0), H_ - 1), h1c = min(max(h1, 0), H_ - 1);
    int w0c = min(max(w0i, 0), W_ - 1), w1c = min(max(w1, 0), W_ - 1);
    float omlh = 1.f - lh, omlw = 1.f - lw;
    float g00 = (tok & h0ok & w0ok) ? omlh * omlw : 0.f;
    float g01 = (tok & h0ok & w1ok) ? omlh * lw : 0.f;
    float g10 = (tok & h1ok & w0ok) ? lh * omlw : 0.f;
    float g11 = (tok & h1ok & w1ok) ? lh * lw : 0.f;

    // lane lerps 16 channels grp*16..+15 of point pt (round-3 layout)
    const unsigned short* bt = xclb + (size_t)(t2c * HW_) * 64 + grp * 16;
    int i00 = (h0c * W_ + w0c) * 64;
    int i01 = (h0c * W_ + w1c) * 64;
    int i10 = (h1c * W_ + w0c) * 64;
    int i11 = (h1c * W_ + w1c) * 64;
    u32x4 A0 = *(const u32x4*)(bt + i00), A1 = *(const u32x4*)(bt + i00 + 8);
    u32x4 B0 = *(const u32x4*)(bt + i01), B1 = *(const u32x4*)(bt + i01 + 8);
    u32x4 C0 = *(const u32x4*)(bt + i10), C1 = *(const u32x4*)(bt + i10 + 8);
    u32x4 D0 = *(const u32x4*)(bt + i11), D1 = *(const u32x4*)(bt + i11 + 8);

#define LERPU(a, b, c, d)                                                   \
  pack2(g00 * blo(a) + g01 * blo(b) + g10 * blo(c) + g11 * blo(d),          \
        g00 * bhi(a) + g01 * bhi(b) + g10 * bhi(c) + g11 * bhi(d))
    u32x4 v0, v1;
    v0[0] = LERPU(A0[0], B0[0], C0[0], D0[0]);
    v0[1] = LERPU(A0[1], B0[1], C0[1], D0[1]);
    v0[2] = LERPU(A0[2], B0[2], C0[2], D0[2]);
    v0[3] = LERPU(A0[3], B0[3], C0[3], D0[3]);
    v1[0] = LERPU(A1[0], B1[0], C1[0], D1[0]);
    v1[1] = LERPU(A1[1], B1[1], C1[1], D1[1]);
    v1[2] = LERPU(A1[2], B1[2], C1[2], D1[2]);
    v1[3] = LERPU(A1[3], B1[3], C1[3], D1[3]);
#undef LERPU

    *(u32x4*)&sA[wid][kk & 1][pt][grp * 16] = v0;
    *(u32x4*)&sA[wid][kk & 1][pt][grp * 16 + 8] = v1;
    __builtin_amdgcn_wave_barrier();   // same-wave LDS is in-order; fence compiler only

    short8 af0 = *(const short8*)&sA[wid][kk & 1][pt][grp * 8];
    short8 af1 = *(const short8*)&sA[wid][kk & 1][pt][32 + grp * 8];
    const unsigned short* wp = wB + ((size_t)k * 64 + pt) * 64 + grp * 8;
    short8 b00 = *(const short8*)(wp);
    short8 b01 = *(const short8*)(wp + 32);
    short8 b10 = *(const short8*)(wp + 16 * 64);
    short8 b11 = *(const short8*)(wp + 16 * 64 + 32);
    short8 b20 = *(const short8*)(wp + 32 * 64);
    short8 b21 = *(const short8*)(wp + 32 * 64 + 32);
    short8 b30 = *(const short8*)(wp + 48 * 64);
    short8 b31 = *(const short8*)(wp + 48 * 64 + 32);
    acc0 = __builtin_amdgcn_mfma_f32_16x16x32_bf16(af0, b00, acc0, 0, 0, 0);
    acc0 = __builtin_amdgcn_mfma_f32_16x16x32_bf16(af1, b01, acc0, 0, 0, 0);
    acc1 = __builtin_amdgcn_mfma_f32_16x16x32_bf16(af0, b10, acc1, 0, 0, 0);
    acc1 = __builtin_amdgcn_mfma_f32_16x16x32_bf16(af1, b11, acc1, 0, 0, 0);
    acc2 = __builtin_amdgcn_mfma_f32_16x16x32_bf16(af0, b20, acc2, 0, 0, 0);
    acc2 = __builtin_amdgcn_mfma_f32_16x16x32_bf16(af1, b21, acc2, 0, 0, 0);
    acc3 = __builtin_amdgcn_mfma_f32_16x16x32_bf16(af0, b30, acc3, 0, 0, 0);
    acc3 = __builtin_amdgcn_mfma_f32_16x16x32_bf16(af1, b31, acc3, 0, 0, 0);
  }

  red[wid][0][lane] = acc0;
  red[wid][1][lane] = acc1;
  red[wid][2][lane] = acc2;
  red[wid][3][lane] = acc3;
  __syncthreads();
  f32x4 s = red[0][wid][lane];
  s = s + red[1][wid][lane];
  s = s + red[2][wid][lane];
  s = s + red[3][wid][lane];

  int ch = wid * 16 + pt;
  float bb = bias[ch];
#pragma unroll
  for (int r = 0; r < 4; ++r) {
    int p = p0 + grp * 4 + r;
    float v = s[r] + bb;
    if (MODE == 0) {
      v = (v >= 0.f) ? v : 0.1f * v;
      outb[(size_t)p * 64 + ch] = f2bf(v);
    } else {
      out32[(size_t)ch * P_ + p] = v + resid[(size_t)ch * P_ + p];
    }
  }
}

extern "C" void kernel_launch(void* const* d_in, const int* in_sizes, int n_in,
                              void* d_out, int out_size, void* d_ws, size_t ws_size,
                              hipStream_t stream) {
  const float* x      = (const float*)d_in[0];
  const float* w_off0 = (const float*)d_in[1];
  const float* b_off0 = (const float*)d_in[2];
  const float* w0     = (const float*)d_in[3];
  const float* b0     = (const float*)d_in[4];
  const float* w_off1 = (const float*)d_in[5];
  const float* b_off1 = (const float*)d_in[6];
  const float* w1     = (const float*)d_in[7];
  const float* b1     = (const float*)d_in[8];
  float* out = (float*)d_out;

  char* base = (char*)d_ws;
  unsigned short* x_clb = (unsigned short*)base;               // 2,064,384 B
  unsigned short* h_clb = (unsigned short*)(base + 2064384);   // 2,064,384 B
  float*          offt  = (float*)(base + 4128768);            // 3,612,672 B
  unsigned short* wA0   = (unsigned short*)(base + 7741440);   // 221,184 B
  unsigned short* wA1   = (unsigned short*)(base + 7962624);
  unsigned short* wB0   = (unsigned short*)(base + 8183808);
  unsigned short* wB1   = (unsigned short*)(base + 8404992);   // end ~8.6 MB

  hipLaunchKernelGGL(k_prep_x, dim3(252), dim3(256), 0, stream, x, x_clb);
  hipLaunchKernelGGL(k_prep_w4, dim3(432, 4), dim3(256), 0, stream,
                     w_off0, w_off1, w0, w1, wA0, wA1, wB0, wB1);

  // layer 0
  hipLaunchKernelGGL(k_off4w, dim3(1008), dim3(256), 0, stream, x_clb, wA0, b_off0, offt);
  hipLaunchKernelGGL((k_samp4w<0>), dim3(1008), dim3(256), 0, stream,
                     x_clb, offt, wB0, b0, (const float*)nullptr, (float*)nullptr, h_clb);

  // layer 1
  hipLaunchKernelGGL(k_off4w, dim3(1008), dim3(256), 0, stream, h_clb, wA1, b_off1, offt);
  hipLaunchKernelGGL((k_samp4w<1>), dim3(1008), dim3(256), 0, stream,
                     h_clb, offt, wB1, b1, x, out, (unsigned short*)nullptr);
}

// Round 7
// 100.379 us; speedup vs baseline: 11.4282x; 1.7851x over previous
//
#include <hip/hip_runtime.h>

#define T_ 7
#define H_ 48
#define W_ 48
#define P_ 16128      // T_*H_*W_
#define HW_ 2304

typedef __attribute__((ext_vector_type(8))) short short8;
typedef __attribute__((ext_vector_type(4))) float f32x4;
typedef __attribute__((ext_vector_type(4))) unsigned u32x4;

__device__ __forceinline__ unsigned short f2bf(float f) {
  union { float f; unsigned u; } x{f};
  unsigned r = x.u + 0x7FFFu + ((x.u >> 16) & 1u);
  return (unsigned short)(r >> 16);
}
__device__ __forceinline__ float blo(unsigned u) {
  union { unsigned u; float f; } x{u << 16};
  return x.f;
}
__device__ __forceinline__ float bhi(unsigned u) {
  union { unsigned u; float f; } x{u & 0xFFFF0000u};
  return x.f;
}
__device__ __forceinline__ unsigned pack2(float a, float b) {
  return (unsigned)f2bf(a) | ((unsigned)f2bf(b) << 16);
}

// ---------- x [64][P] fp32 -> x_clb [P][64] bf16 ----------
__global__ void k_prep_x(const float* __restrict__ in, unsigned short* __restrict__ outb) {
  __shared__ float tile[64][65];
  int p0 = blockIdx.x * 64;
  int l = threadIdx.x & 63;
  int g = threadIdx.x >> 6;
#pragma unroll
  for (int i = 0; i < 16; ++i) {
    int c = g * 16 + i;
    tile[c][l] = in[c * P_ + p0 + l];
  }
  __syncthreads();
#pragma unroll
  for (int i = 0; i < 16; ++i) {
    int p = g * 16 + i;
    outb[(p0 + p) * 64 + l] = f2bf(tile[l][p]);
  }
}

// ---------- weights [OC][64][27] fp32 -> fragment-swizzled bf16 ----------
// layout: [27 k][4 nt][2 kc][64 lane][8 j] ; o = nt*16 + (lane&15), c = kc*32 + (lane>>4)*8 + j
__global__ void k_prep_w4(const float* __restrict__ s0, const float* __restrict__ s1,
                          const float* __restrict__ s2, const float* __restrict__ s3,
                          unsigned short* __restrict__ d0, unsigned short* __restrict__ d1,
                          unsigned short* __restrict__ d2, unsigned short* __restrict__ d3) {
  int y = blockIdx.y;
  const float* w = (y == 0) ? s0 : (y == 1) ? s1 : (y == 2) ? s2 : s3;
  unsigned short* wt = (y == 0) ? d0 : (y == 1) ? d1 : (y == 2) ? d2 : d3;
  int OC = (y < 2) ? 54 : 64;
  int idx = blockIdx.x * 256 + threadIdx.x;   // < 110592
  int j = idx & 7;
  int l = (idx >> 3) & 63;
  int kc = (idx >> 9) & 1;
  int nt = (idx >> 10) & 3;
  int k = idx >> 12;
  int o = nt * 16 + (l & 15);
  int c = kc * 32 + (l >> 4) * 8 + j;
  wt[idx] = (o < OC) ? f2bf(w[(o * 64 + c) * 27 + k]) : (unsigned short)0;
}

// ---------- offset conv: M=32, 4 waves split 27 taps (7/7/7/6+phantom) ----------
// xclb [P][64] bf16; wAs swizzled; out offt2 [27][P][2] fp32
__global__ __launch_bounds__(256) void k_off4w(const unsigned short* __restrict__ xclb,
                                               const unsigned short* __restrict__ wAs,
                                               const float* __restrict__ boff,
                                               float* __restrict__ offt2) {
  __shared__ f32x4 red[4][4][64];
  int p0 = blockIdx.x * 32;
  int t = p0 / HW_;
  int r0 = p0 - t * HW_;
  int h0r = r0 / W_;
  int w0s = r0 - h0r * W_;               // in {0,16,32}
  int h1r = h0r + (w0s == 32 ? 1 : 0);
  int w1s = (w0s == 32) ? 0 : w0s + 16;
  int tid = threadIdx.x;
  int lane = tid & 63, wid = tid >> 6;
  int pt = lane & 15, grp = lane >> 4;

  f32x4 zacc{0.f, 0.f, 0.f, 0.f};
  f32x4 aA0 = zacc, aA1 = zacc, aA2 = zacc, aA3 = zacc;
  f32x4 aB0 = zacc, aB1 = zacc, aB2 = zacc, aB3 = zacc;
  const short8 zero8{0, 0, 0, 0, 0, 0, 0, 0};
  int kbeg = wid * 7;

#pragma unroll
  for (int kk = 0; kk < 7; ++kk) {
    int kraw = kbeg + kk;                 // 0..27 (27 = phantom, masked)
    int k = min(kraw, 26);
    int kt = k / 9;
    int r9 = k - kt * 9;
    int kh = r9 / 3;
    int kw = r9 - (r9 / 3) * 3;
    int t2 = t + kt - 1;
    bool tok = (kraw < 27) & ((unsigned)t2 < (unsigned)T_);
    int t2c = min(max(t2, 0), T_ - 1);

    // swizzled weights: 8 contiguous 1KB loads
    const unsigned short* wp = wAs + (size_t)k * 4096 + lane * 8;
    short8 b00 = *(const short8*)(wp);
    short8 b01 = *(const short8*)(wp + 512);
    short8 b10 = *(const short8*)(wp + 1024);
    short8 b11 = *(const short8*)(wp + 1536);
    short8 b20 = *(const short8*)(wp + 2048);
    short8 b21 = *(const short8*)(wp + 2560);
    short8 b30 = *(const short8*)(wp + 3072);
    short8 b31 = *(const short8*)(wp + 3584);

    // frag A: points p0..p0+15  (row h0r, w start w0s)
    {
      int h2 = h0r + kh - 1;
      int w2 = w0s + pt + kw - 1;
      bool ok = tok & ((unsigned)h2 < (unsigned)H_) & ((unsigned)w2 < (unsigned)W_);
      int h2c = min(max(h2, 0), H_ - 1);
      int w2c = min(max(w2, 0), W_ - 1);
      const unsigned short* ap = xclb + ((size_t)(t2c * HW_ + h2c * W_ + w2c) * 64 + grp * 8);
      short8 a0 = *(const short8*)ap;
      short8 a1 = *(const short8*)(ap + 32);
      a0 = ok ? a0 : zero8;
      a1 = ok ? a1 : zero8;
      aA0 = __builtin_amdgcn_mfma_f32_16x16x32_bf16(a0, b00, aA0, 0, 0, 0);
      aA0 = __builtin_amdgcn_mfma_f32_16x16x32_bf16(a1, b01, aA0, 0, 0, 0);
      aA1 = __builtin_amdgcn_mfma_f32_16x16x32_bf16(a0, b10, aA1, 0, 0, 0);
      aA1 = __builtin_amdgcn_mfma_f32_16x16x32_bf16(a1, b11, aA1, 0, 0, 0);
      aA2 = __builtin_amdgcn_mfma_f32_16x16x32_bf16(a0, b20, aA2, 0, 0, 0);
      aA2 = __builtin_amdgcn_mfma_f32_16x16x32_bf16(a1, b21, aA2, 0, 0, 0);
      aA3 = __builtin_amdgcn_mfma_f32_16x16x32_bf16(a0, b30, aA3, 0, 0, 0);
      aA3 = __builtin_amdgcn_mfma_f32_16x16x32_bf16(a1, b31, aA3, 0, 0, 0);
    }
    // frag B: points p0+16..p0+31 (row h1r, w start w1s)
    {
      int h2 = h1r + kh - 1;
      int w2 = w1s + pt + kw - 1;
      bool ok = tok & ((unsigned)h2 < (unsigned)H_) & ((unsigned)w2 < (unsigned)W_);
      int h2c = min(max(h2, 0), H_ - 1);
      int w2c = min(max(w2, 0), W_ - 1);
      const unsigned short* ap = xclb + ((size_t)(t2c * HW_ + h2c * W_ + w2c) * 64 + grp * 8);
      short8 a0 = *(const short8*)ap;
      short8 a1 = *(const short8*)(ap + 32);
      a0 = ok ? a0 : zero8;
      a1 = ok ? a1 : zero8;
      aB0 = __builtin_amdgcn_mfma_f32_16x16x32_bf16(a0, b00, aB0, 0, 0, 0);
      aB0 = __builtin_amdgcn_mfma_f32_16x16x32_bf16(a1, b01, aB0, 0, 0, 0);
      aB1 = __builtin_amdgcn_mfma_f32_16x16x32_bf16(a0, b10, aB1, 0, 0, 0);
      aB1 = __builtin_amdgcn_mfma_f32_16x16x32_bf16(a1, b11, aB1, 0, 0, 0);
      aB2 = __builtin_amdgcn_mfma_f32_16x16x32_bf16(a0, b20, aB2, 0, 0, 0);
      aB2 = __builtin_amdgcn_mfma_f32_16x16x32_bf16(a1, b21, aB2, 0, 0, 0);
      aB3 = __builtin_amdgcn_mfma_f32_16x16x32_bf16(a0, b30, aB3, 0, 0, 0);
      aB3 = __builtin_amdgcn_mfma_f32_16x16x32_bf16(a1, b31, aB3, 0, 0, 0);
    }
  }

  int oc = wid * 16 + pt;
  float bb = (oc < 54) ? boff[oc] : 0.f;
  int kidx = oc >> 1, d = oc & 1;

  // phase 0: frag A
  red[wid][0][lane] = aA0;
  red[wid][1][lane] = aA1;
  red[wid][2][lane] = aA2;
  red[wid][3][lane] = aA3;
  __syncthreads();
  {
    f32x4 s = red[0][wid][lane];
    s = s + red[1][wid][lane];
    s = s + red[2][wid][lane];
    s = s + red[3][wid][lane];
    if (oc < 54) {
#pragma unroll
      for (int r = 0; r < 4; ++r) {
        int p = p0 + grp * 4 + r;
        offt2[((size_t)kidx * P_ + p) * 2 + d] = s[r] + bb;
      }
    }
  }
  __syncthreads();
  // phase 1: frag B
  red[wid][0][lane] = aB0;
  red[wid][1][lane] = aB1;
  red[wid][2][lane] = aB2;
  red[wid][3][lane] = aB3;
  __syncthreads();
  {
    f32x4 s = red[0][wid][lane];
    s = s + red[1][wid][lane];
    s = s + red[2][wid][lane];
    s = s + red[3][wid][lane];
    if (oc < 54) {
#pragma unroll
      for (int r = 0; r < 4; ++r) {
        int p = p0 + 16 + grp * 4 + r;
        offt2[((size_t)kidx * P_ + p) * 2 + d] = s[r] + bb;
      }
    }
  }
}

// ---------- deformable sample + conv: M=32, 4 waves split 27 taps ----------
// xclb [P][64] bf16; offt2 [27][P][2]; wBs swizzled
// MODE 0: leaky -> outb [P][64] bf16.  MODE 1: +bias +resid(x [64][P]) -> out [64][P] f32.
template <int MODE>
__global__ __launch_bounds__(256) void k_samp4w(
    const unsigned short* __restrict__ xclb, const float* __restrict__ offt2,
    const unsigned short* __restrict__ wBs, const float* __restrict__ bias,
    const float* __restrict__ resid, float* __restrict__ out32,
    unsigned short* __restrict__ outb) {
  __shared__ f32x4 red[4][4][64];
  __shared__ unsigned short sA[4][2][16][72];   // [wave][frag][pt][ch]
  int p0 = blockIdx.x * 32;
  int t = p0 / HW_;
  int r0 = p0 - t * HW_;
  int h0r = r0 / W_;
  int w0s = r0 - h0r * W_;               // in {0,16,32}
  int h1r = h0r + (w0s == 32 ? 1 : 0);
  int w1s = (w0s == 32) ? 0 : w0s + 16;
  int tid = threadIdx.x;
  int lane = tid & 63, wid = tid >> 6;
  int pt = lane & 15, grp = lane >> 4;

  f32x4 zacc{0.f, 0.f, 0.f, 0.f};
  f32x4 aA0 = zacc, aA1 = zacc, aA2 = zacc, aA3 = zacc;
  f32x4 aB0 = zacc, aB1 = zacc, aB2 = zacc, aB3 = zacc;
  int kbeg = wid * 7;

#pragma unroll
  for (int kk = 0; kk < 7; ++kk) {
    int kraw = kbeg + kk;                 // 0..27 (27 = phantom, masked)
    int k = min(kraw, 26);
    int kt = k / 9;
    int r9 = k - kt * 9;
    int kh = r9 / 3;
    int kw = r9 - (r9 / 3) * 3;
    int t2 = t + kt - 1;
    bool tok = (kraw < 27) & ((unsigned)t2 < (unsigned)T_);
    int t2c = min(max(t2, 0), T_ - 1);

    // swizzled weights: 8 contiguous 1KB loads
    const unsigned short* wp = wBs + (size_t)k * 4096 + lane * 8;
    short8 b00 = *(const short8*)(wp);
    short8 b01 = *(const short8*)(wp + 512);
    short8 b10 = *(const short8*)(wp + 1024);
    short8 b11 = *(const short8*)(wp + 1536);
    short8 b20 = *(const short8*)(wp + 2048);
    short8 b21 = *(const short8*)(wp + 2560);
    short8 b30 = *(const short8*)(wp + 3072);
    short8 b31 = *(const short8*)(wp + 3584);

#pragma unroll
    for (int f = 0; f < 2; ++f) {
      int hrow = (f == 0) ? h0r : h1r;
      int wst = (f == 0) ? w0s : w1s;
      float2 o2 = *(const float2*)(offt2 + ((size_t)k * P_ + p0 + f * 16 + pt) * 2);
      float ph = (float)(hrow + kh - 1) + o2.x;
      float pw = (float)(wst + pt + kw - 1) + o2.y;
      float hf = floorf(ph), wf = floorf(pw);
      float lh = ph - hf, lw = pw - wf;
      int h0 = (int)hf, w0i = (int)wf;
      int h1 = h0 + 1, w1 = w0i + 1;
      bool h0ok = ((unsigned)h0 < (unsigned)H_), h1ok = ((unsigned)h1 < (unsigned)H_);
      bool w0ok = ((unsigned)w0i < (unsigned)W_), w1ok = ((unsigned)w1 < (unsigned)W_);
      int h0c = min(max(h0, 0), H_ - 1), h1c = min(max(h1, 0), H_ - 1);
      int w0c = min(max(w0i, 0), W_ - 1), w1c = min(max(w1, 0), W_ - 1);
      float omlh = 1.f - lh, omlw = 1.f - lw;
      float g00 = (tok & h0ok & w0ok) ? omlh * omlw : 0.f;
      float g01 = (tok & h0ok & w1ok) ? omlh * lw : 0.f;
      float g10 = (tok & h1ok & w0ok) ? lh * omlw : 0.f;
      float g11 = (tok & h1ok & w1ok) ? lh * lw : 0.f;

      // lane lerps 16 channels grp*16..+15 of its point (round-6 proven path)
      const unsigned short* bt = xclb + (size_t)(t2c * HW_) * 64 + grp * 16;
      int i00 = (h0c * W_ + w0c) * 64;
      int i01 = (h0c * W_ + w1c) * 64;
      int i10 = (h1c * W_ + w0c) * 64;
      int i11 = (h1c * W_ + w1c) * 64;
      u32x4 A0 = *(const u32x4*)(bt + i00), A1 = *(const u32x4*)(bt + i00 + 8);
      u32x4 B0 = *(const u32x4*)(bt + i01), B1 = *(const u32x4*)(bt + i01 + 8);
      u32x4 C0 = *(const u32x4*)(bt + i10), C1 = *(const u32x4*)(bt + i10 + 8);
      u32x4 D0 = *(const u32x4*)(bt + i11), D1 = *(const u32x4*)(bt + i11 + 8);

#define LERPU(a, b, c, d)                                                   \
  pack2(g00 * blo(a) + g01 * blo(b) + g10 * blo(c) + g11 * blo(d),          \
        g00 * bhi(a) + g01 * bhi(b) + g10 * bhi(c) + g11 * bhi(d))
      u32x4 v0, v1;
      v0[0] = LERPU(A0[0], B0[0], C0[0], D0[0]);
      v0[1] = LERPU(A0[1], B0[1], C0[1], D0[1]);
      v0[2] = LERPU(A0[2], B0[2], C0[2], D0[2]);
      v0[3] = LERPU(A0[3], B0[3], C0[3], D0[3]);
      v1[0] = LERPU(A1[0], B1[0], C1[0], D1[0]);
      v1[1] = LERPU(A1[1], B1[1], C1[1], D1[1]);
      v1[2] = LERPU(A1[2], B1[2], C1[2], D1[2]);
      v1[3] = LERPU(A1[3], B1[3], C1[3], D1[3]);
#undef LERPU

      __builtin_amdgcn_wave_barrier();
      *(u32x4*)&sA[wid][f][pt][grp * 16] = v0;
      *(u32x4*)&sA[wid][f][pt][grp * 16 + 8] = v1;
      __builtin_amdgcn_wave_barrier();   // same-wave LDS is in-order; fence compiler only

      short8 af0 = *(const short8*)&sA[wid][f][pt][grp * 8];
      short8 af1 = *(const short8*)&sA[wid][f][pt][32 + grp * 8];
      __builtin_amdgcn_wave_barrier();

      if (f == 0) {
        aA0 = __builtin_amdgcn_mfma_f32_16x16x32_bf16(af0, b00, aA0, 0, 0, 0);
        aA0 = __builtin_amdgcn_mfma_f32_16x16x32_bf16(af1, b01, aA0, 0, 0, 0);
        aA1 = __builtin_amdgcn_mfma_f32_16x16x32_bf16(af0, b10, aA1, 0, 0, 0);
        aA1 = __builtin_amdgcn_mfma_f32_16x16x32_bf16(af1, b11, aA1, 0, 0, 0);
        aA2 = __builtin_amdgcn_mfma_f32_16x16x32_bf16(af0, b20, aA2, 0, 0, 0);
        aA2 = __builtin_amdgcn_mfma_f32_16x16x32_bf16(af1, b21, aA2, 0, 0, 0);
        aA3 = __builtin_amdgcn_mfma_f32_16x16x32_bf16(af0, b30, aA3, 0, 0, 0);
        aA3 = __builtin_amdgcn_mfma_f32_16x16x32_bf16(af1, b31, aA3, 0, 0, 0);
      } else {
        aB0 = __builtin_amdgcn_mfma_f32_16x16x32_bf16(af0, b00, aB0, 0, 0, 0);
        aB0 = __builtin_amdgcn_mfma_f32_16x16x32_bf16(af1, b01, aB0, 0, 0, 0);
        aB1 = __builtin_amdgcn_mfma_f32_16x16x32_bf16(af0, b10, aB1, 0, 0, 0);
        aB1 = __builtin_amdgcn_mfma_f32_16x16x32_bf16(af1, b11, aB1, 0, 0, 0);
        aB2 = __builtin_amdgcn_mfma_f32_16x16x32_bf16(af0, b20, aB2, 0, 0, 0);
        aB2 = __builtin_amdgcn_mfma_f32_16x16x32_bf16(af1, b21, aB2, 0, 0, 0);
        aB3 = __builtin_amdgcn_mfma_f32_16x16x32_bf16(af0, b30, aB3, 0, 0, 0);
        aB3 = __builtin_amdgcn_mfma_f32_16x16x32_bf16(af1, b31, aB3, 0, 0, 0);
      }
    }
  }

  int ch = wid * 16 + pt;
  float bb = bias[ch];

  // phase 0: frag A
  red[wid][0][lane] = aA0;
  red[wid][1][lane] = aA1;
  red[wid][2][lane] = aA2;
  red[wid][3][lane] = aA3;
  __syncthreads();
  {
    f32x4 s = red[0][wid][lane];
    s = s + red[1][wid][lane];
    s = s + red[2][wid][lane];
    s = s + red[3][wid][lane];
#pragma unroll
    for (int r = 0; r < 4; ++r) {
      int p = p0 + grp * 4 + r;
      float v = s[r] + bb;
      if (MODE == 0) {
        v = (v >= 0.f) ? v : 0.1f * v;
        outb[(size_t)p * 64 + ch] = f2bf(v);
      } else {
        out32[(size_t)ch * P_ + p] = v + resid[(size_t)ch * P_ + p];
      }
    }
  }
  __syncthreads();
  // phase 1: frag B
  red[wid][0][lane] = aB0;
  red[wid][1][lane] = aB1;
  red[wid][2][lane] = aB2;
  red[wid][3][lane] = aB3;
  __syncthreads();
  {
    f32x4 s = red[0][wid][lane];
    s = s + red[1][wid][lane];
    s = s + red[2][wid][lane];
    s = s + red[3][wid][lane];
#pragma unroll
    for (int r = 0; r < 4; ++r) {
      int p = p0 + 16 + grp * 4 + r;
      float v = s[r] + bb;
      if (MODE == 0) {
        v = (v >= 0.f) ? v : 0.1f * v;
        outb[(size_t)p * 64 + ch] = f2bf(v);
      } else {
        out32[(size_t)ch * P_ + p] = v + resid[(size_t)ch * P_ + p];
      }
    }
  }
}

extern "C" void kernel_launch(void* const* d_in, const int* in_sizes, int n_in,
                              void* d_out, int out_size, void* d_ws, size_t ws_size,
                              hipStream_t stream) {
  const float* x      = (const float*)d_in[0];
  const float* w_off0 = (const float*)d_in[1];
  const float* b_off0 = (const float*)d_in[2];
  const float* w0     = (const float*)d_in[3];
  const float* b0     = (const float*)d_in[4];
  const float* w_off1 = (const float*)d_in[5];
  const float* b_off1 = (const float*)d_in[6];
  const float* w1     = (const float*)d_in[7];
  const float* b1     = (const float*)d_in[8];
  float* out = (float*)d_out;

  char* base = (char*)d_ws;
  unsigned short* x_clb = (unsigned short*)base;               // 2,064,384 B
  unsigned short* h_clb = (unsigned short*)(base + 2064384);   // 2,064,384 B
  float*          offt2 = (float*)(base + 4128768);            // 3,483,648 B
  unsigned short* wA0   = (unsigned short*)(base + 7612416);   // 221,184 B
  unsigned short* wA1   = (unsigned short*)(base + 7833600);
  unsigned short* wB0   = (unsigned short*)(base + 8054784);
  unsigned short* wB1   = (unsigned short*)(base + 8275968);   // end ~8.5 MB

  hipLaunchKernelGGL(k_prep_x, dim3(252), dim3(256), 0, stream, x, x_clb);
  hipLaunchKernelGGL(k_prep_w4, dim3(432, 4), dim3(256), 0, stream,
                     w_off0, w_off1, w0, w1, wA0, wA1, wB0, wB1);

  // layer 0
  hipLaunchKernelGGL(k_off4w, dim3(504), dim3(256), 0, stream, x_clb, wA0, b_off0, offt2);
  hipLaunchKernelGGL((k_samp4w<0>), dim3(504), dim3(256), 0, stream,
                     x_clb, offt2, wB0, b0, (const float*)nullptr, (float*)nullptr, h_clb);

  // layer 1
  hipLaunchKernelGGL(k_off4w, dim3(504), dim3(256), 0, stream, h_clb, wA1, b_off1, offt2);
  hipLaunchKernelGGL((k_samp4w<1>), dim3(504), dim3(256), 0, stream,
                     h_clb, offt2, wB1, b1, x, out, (unsigned short*)nullptr);
}

// Round 8
// 99.668 us; speedup vs baseline: 11.5097x; 1.0071x over previous
//
#include <hip/hip_runtime.h>

#define T_ 7
#define H_ 48
#define W_ 48
#define P_ 16128      // T_*H_*W_
#define HW_ 2304

typedef __attribute__((ext_vector_type(8))) short short8;
typedef __attribute__((ext_vector_type(4))) float f32x4;
typedef __attribute__((ext_vector_type(4))) unsigned u32x4;

__device__ __forceinline__ unsigned short f2bf(float f) {
  union { float f; unsigned u; } x{f};
  unsigned r = x.u + 0x7FFFu + ((x.u >> 16) & 1u);
  return (unsigned short)(r >> 16);
}
__device__ __forceinline__ float blo(unsigned u) {
  union { unsigned u; float f; } x{u << 16};
  return x.f;
}
__device__ __forceinline__ float bhi(unsigned u) {
  union { unsigned u; float f; } x{u & 0xFFFF0000u};
  return x.f;
}
__device__ __forceinline__ unsigned pack2(float a, float b) {
  return (unsigned)f2bf(a) | ((unsigned)f2bf(b) << 16);
}
// bijective XCD swizzle: consecutive output blocks land on the SAME XCD,
// so each XCD's private 4MB L2 holds one contiguous p-slab (nwg % 8 == 0).
__device__ __forceinline__ int xcd_swz(int bid, int nwg) {
  int cpx = nwg >> 3;
  return (bid & 7) * cpx + (bid >> 3);
}

// ---------- x [64][P] fp32 -> x_clb [P][64] bf16 ----------
__global__ void k_prep_x(const float* __restrict__ in, unsigned short* __restrict__ outb) {
  __shared__ float tile[64][65];
  int p0 = blockIdx.x * 64;
  int l = threadIdx.x & 63;
  int g = threadIdx.x >> 6;
#pragma unroll
  for (int i = 0; i < 16; ++i) {
    int c = g * 16 + i;
    tile[c][l] = in[c * P_ + p0 + l];
  }
  __syncthreads();
#pragma unroll
  for (int i = 0; i < 16; ++i) {
    int p = g * 16 + i;
    outb[(p0 + p) * 64 + l] = f2bf(tile[l][p]);
  }
}

// ---------- weights [OC][64][27] fp32 -> fragment-swizzled bf16 ----------
// layout: [27 k][4 nt][2 kc][64 lane][8 j] ; o = nt*16 + (lane&15), c = kc*32 + (lane>>4)*8 + j
__global__ void k_prep_w4(const float* __restrict__ s0, const float* __restrict__ s1,
                          const float* __restrict__ s2, const float* __restrict__ s3,
                          unsigned short* __restrict__ d0, unsigned short* __restrict__ d1,
                          unsigned short* __restrict__ d2, unsigned short* __restrict__ d3) {
  int y = blockIdx.y;
  const float* w = (y == 0) ? s0 : (y == 1) ? s1 : (y == 2) ? s2 : s3;
  unsigned short* wt = (y == 0) ? d0 : (y == 1) ? d1 : (y == 2) ? d2 : d3;
  int OC = (y < 2) ? 54 : 64;
  int idx = blockIdx.x * 256 + threadIdx.x;   // < 110592
  int j = idx & 7;
  int l = (idx >> 3) & 63;
  int kc = (idx >> 9) & 1;
  int nt = (idx >> 10) & 3;
  int k = idx >> 12;
  int o = nt * 16 + (l & 15);
  int c = kc * 32 + (l >> 4) * 8 + j;
  wt[idx] = (o < OC) ? f2bf(w[(o * 64 + c) * 27 + k]) : (unsigned short)0;
}

// ---------- offset conv: M=32, 4 waves split 27 taps (7/7/7/6+phantom) ----------
// xclb [P][64] bf16; wAs swizzled; out offt2 [27][P][2] fp32
__global__ __launch_bounds__(256) void k_off4w(const unsigned short* __restrict__ xclb,
                                               const unsigned short* __restrict__ wAs,
                                               const float* __restrict__ boff,
                                               float* __restrict__ offt2) {
  __shared__ f32x4 red[4][4][64];
  int p0 = xcd_swz(blockIdx.x, gridDim.x) * 32;
  int t = p0 / HW_;
  int r0 = p0 - t * HW_;
  int h0r = r0 / W_;
  int w0s = r0 - h0r * W_;               // in {0,16,32}
  int h1r = h0r + (w0s == 32 ? 1 : 0);
  int w1s = (w0s == 32) ? 0 : w0s + 16;
  int tid = threadIdx.x;
  int lane = tid & 63, wid = tid >> 6;
  int pt = lane & 15, grp = lane >> 4;

  f32x4 zacc{0.f, 0.f, 0.f, 0.f};
  f32x4 aA0 = zacc, aA1 = zacc, aA2 = zacc, aA3 = zacc;
  f32x4 aB0 = zacc, aB1 = zacc, aB2 = zacc, aB3 = zacc;
  const short8 zero8{0, 0, 0, 0, 0, 0, 0, 0};
  int kbeg = wid * 7;

#pragma unroll
  for (int kk = 0; kk < 7; ++kk) {
    int kraw = kbeg + kk;                 // 0..27 (27 = phantom, masked)
    int k = min(kraw, 26);
    int kt = k / 9;
    int r9 = k - kt * 9;
    int kh = r9 / 3;
    int kw = r9 - (r9 / 3) * 3;
    int t2 = t + kt - 1;
    bool tok = (kraw < 27) & ((unsigned)t2 < (unsigned)T_);
    int t2c = min(max(t2, 0), T_ - 1);

    // swizzled weights: 8 contiguous 1KB loads
    const unsigned short* wp = wAs + (size_t)k * 4096 + lane * 8;
    short8 b00 = *(const short8*)(wp);
    short8 b01 = *(const short8*)(wp + 512);
    short8 b10 = *(const short8*)(wp + 1024);
    short8 b11 = *(const short8*)(wp + 1536);
    short8 b20 = *(const short8*)(wp + 2048);
    short8 b21 = *(const short8*)(wp + 2560);
    short8 b30 = *(const short8*)(wp + 3072);
    short8 b31 = *(const short8*)(wp + 3584);

    // frag A: points p0..p0+15  (row h0r, w start w0s)
    {
      int h2 = h0r + kh - 1;
      int w2 = w0s + pt + kw - 1;
      bool ok = tok & ((unsigned)h2 < (unsigned)H_) & ((unsigned)w2 < (unsigned)W_);
      int h2c = min(max(h2, 0), H_ - 1);
      int w2c = min(max(w2, 0), W_ - 1);
      const unsigned short* ap = xclb + ((size_t)(t2c * HW_ + h2c * W_ + w2c) * 64 + grp * 8);
      short8 a0 = *(const short8*)ap;
      short8 a1 = *(const short8*)(ap + 32);
      a0 = ok ? a0 : zero8;
      a1 = ok ? a1 : zero8;
      aA0 = __builtin_amdgcn_mfma_f32_16x16x32_bf16(a0, b00, aA0, 0, 0, 0);
      aA0 = __builtin_amdgcn_mfma_f32_16x16x32_bf16(a1, b01, aA0, 0, 0, 0);
      aA1 = __builtin_amdgcn_mfma_f32_16x16x32_bf16(a0, b10, aA1, 0, 0, 0);
      aA1 = __builtin_amdgcn_mfma_f32_16x16x32_bf16(a1, b11, aA1, 0, 0, 0);
      aA2 = __builtin_amdgcn_mfma_f32_16x16x32_bf16(a0, b20, aA2, 0, 0, 0);
      aA2 = __builtin_amdgcn_mfma_f32_16x16x32_bf16(a1, b21, aA2, 0, 0, 0);
      aA3 = __builtin_amdgcn_mfma_f32_16x16x32_bf16(a0, b30, aA3, 0, 0, 0);
      aA3 = __builtin_amdgcn_mfma_f32_16x16x32_bf16(a1, b31, aA3, 0, 0, 0);
    }
    // frag B: points p0+16..p0+31 (row h1r, w start w1s)
    {
      int h2 = h1r + kh - 1;
      int w2 = w1s + pt + kw - 1;
      bool ok = tok & ((unsigned)h2 < (unsigned)H_) & ((unsigned)w2 < (unsigned)W_);
      int h2c = min(max(h2, 0), H_ - 1);
      int w2c = min(max(w2, 0), W_ - 1);
      const unsigned short* ap = xclb + ((size_t)(t2c * HW_ + h2c * W_ + w2c) * 64 + grp * 8);
      short8 a0 = *(const short8*)ap;
      short8 a1 = *(const short8*)(ap + 32);
      a0 = ok ? a0 : zero8;
      a1 = ok ? a1 : zero8;
      aB0 = __builtin_amdgcn_mfma_f32_16x16x32_bf16(a0, b00, aB0, 0, 0, 0);
      aB0 = __builtin_amdgcn_mfma_f32_16x16x32_bf16(a1, b01, aB0, 0, 0, 0);
      aB1 = __builtin_amdgcn_mfma_f32_16x16x32_bf16(a0, b10, aB1, 0, 0, 0);
      aB1 = __builtin_amdgcn_mfma_f32_16x16x32_bf16(a1, b11, aB1, 0, 0, 0);
      aB2 = __builtin_amdgcn_mfma_f32_16x16x32_bf16(a0, b20, aB2, 0, 0, 0);
      aB2 = __builtin_amdgcn_mfma_f32_16x16x32_bf16(a1, b21, aB2, 0, 0, 0);
      aB3 = __builtin_amdgcn_mfma_f32_16x16x32_bf16(a0, b30, aB3, 0, 0, 0);
      aB3 = __builtin_amdgcn_mfma_f32_16x16x32_bf16(a1, b31, aB3, 0, 0, 0);
    }
  }

  int oc = wid * 16 + pt;
  float bb = (oc < 54) ? boff[oc] : 0.f;
  int kidx = oc >> 1, d = oc & 1;

  // phase 0: frag A
  red[wid][0][lane] = aA0;
  red[wid][1][lane] = aA1;
  red[wid][2][lane] = aA2;
  red[wid][3][lane] = aA3;
  __syncthreads();
  {
    f32x4 s = red[0][wid][lane];
    s = s + red[1][wid][lane];
    s = s + red[2][wid][lane];
    s = s + red[3][wid][lane];
    if (oc < 54) {
#pragma unroll
      for (int r = 0; r < 4; ++r) {
        int p = p0 + grp * 4 + r;
        offt2[((size_t)kidx * P_ + p) * 2 + d] = s[r] + bb;
      }
    }
  }
  __syncthreads();
  // phase 1: frag B
  red[wid][0][lane] = aB0;
  red[wid][1][lane] = aB1;
  red[wid][2][lane] = aB2;
  red[wid][3][lane] = aB3;
  __syncthreads();
  {
    f32x4 s = red[0][wid][lane];
    s = s + red[1][wid][lane];
    s = s + red[2][wid][lane];
    s = s + red[3][wid][lane];
    if (oc < 54) {
#pragma unroll
      for (int r = 0; r < 4; ++r) {
        int p = p0 + 16 + grp * 4 + r;
        offt2[((size_t)kidx * P_ + p) * 2 + d] = s[r] + bb;
      }
    }
  }
}

// ---------- deformable sample + conv: M=32, 4 waves split 27 taps ----------
// xclb [P][64] bf16; offt2 [27][P][2]; wBs swizzled
// MODE 0: leaky -> outb [P][64] bf16.  MODE 1: +bias +resid(x [64][P]) -> out [64][P] f32.
template <int MODE>
__global__ __launch_bounds__(256) void k_samp4w(
    const unsigned short* __restrict__ xclb, const float* __restrict__ offt2,
    const unsigned short* __restrict__ wBs, const float* __restrict__ bias,
    const float* __restrict__ resid, float* __restrict__ out32,
    unsigned short* __restrict__ outb) {
  __shared__ f32x4 red[4][4][64];
  __shared__ unsigned short sA[4][2][16][72];   // [wave][frag][pt][ch]
  int p0 = xcd_swz(blockIdx.x, gridDim.x) * 32;
  int t = p0 / HW_;
  int r0 = p0 - t * HW_;
  int h0r = r0 / W_;
  int w0s = r0 - h0r * W_;               // in {0,16,32}
  int h1r = h0r + (w0s == 32 ? 1 : 0);
  int w1s = (w0s == 32) ? 0 : w0s + 16;
  int tid = threadIdx.x;
  int lane = tid & 63, wid = tid >> 6;
  int pt = lane & 15, grp = lane >> 4;

  f32x4 zacc{0.f, 0.f, 0.f, 0.f};
  f32x4 aA0 = zacc, aA1 = zacc, aA2 = zacc, aA3 = zacc;
  f32x4 aB0 = zacc, aB1 = zacc, aB2 = zacc, aB3 = zacc;
  int kbeg = wid * 7;

#pragma unroll
  for (int kk = 0; kk < 7; ++kk) {
    int kraw = kbeg + kk;                 // 0..27 (27 = phantom, masked)
    int k = min(kraw, 26);
    int kt = k / 9;
    int r9 = k - kt * 9;
    int kh = r9 / 3;
    int kw = r9 - (r9 / 3) * 3;
    int t2 = t + kt - 1;
    bool tok = (kraw < 27) & ((unsigned)t2 < (unsigned)T_);
    int t2c = min(max(t2, 0), T_ - 1);

    // swizzled weights: 8 contiguous 1KB loads
    const unsigned short* wp = wBs + (size_t)k * 4096 + lane * 8;
    short8 b00 = *(const short8*)(wp);
    short8 b01 = *(const short8*)(wp + 512);
    short8 b10 = *(const short8*)(wp + 1024);
    short8 b11 = *(const short8*)(wp + 1536);
    short8 b20 = *(const short8*)(wp + 2048);
    short8 b21 = *(const short8*)(wp + 2560);
    short8 b30 = *(const short8*)(wp + 3072);
    short8 b31 = *(const short8*)(wp + 3584);

#pragma unroll
    for (int f = 0; f < 2; ++f) {
      int hrow = (f == 0) ? h0r : h1r;
      int wst = (f == 0) ? w0s : w1s;
      float2 o2 = *(const float2*)(offt2 + ((size_t)k * P_ + p0 + f * 16 + pt) * 2);
      float ph = (float)(hrow + kh - 1) + o2.x;
      float pw = (float)(wst + pt + kw - 1) + o2.y;
      float hf = floorf(ph), wf = floorf(pw);
      float lh = ph - hf, lw = pw - wf;
      int h0 = (int)hf, w0i = (int)wf;
      int h1 = h0 + 1, w1 = w0i + 1;
      bool h0ok = ((unsigned)h0 < (unsigned)H_), h1ok = ((unsigned)h1 < (unsigned)H_);
      bool w0ok = ((unsigned)w0i < (unsigned)W_), w1ok = ((unsigned)w1 < (unsigned)W_);
      int h0c = min(max(h0, 0), H_ - 1), h1c = min(max(h1, 0), H_ - 1);
      int w0c = min(max(w0i, 0), W_ - 1), w1c = min(max(w1, 0), W_ - 1);
      float omlh = 1.f - lh, omlw = 1.f - lw;
      float g00 = (tok & h0ok & w0ok) ? omlh * omlw : 0.f;
      float g01 = (tok & h0ok & w1ok) ? omlh * lw : 0.f;
      float g10 = (tok & h1ok & w0ok) ? lh * omlw : 0.f;
      float g11 = (tok & h1ok & w1ok) ? lh * lw : 0.f;

      // lane lerps 16 channels grp*16..+15 of its point (round-6 proven path)
      const unsigned short* bt = xclb + (size_t)(t2c * HW_) * 64 + grp * 16;
      int i00 = (h0c * W_ + w0c) * 64;
      int i01 = (h0c * W_ + w1c) * 64;
      int i10 = (h1c * W_ + w0c) * 64;
      int i11 = (h1c * W_ + w1c) * 64;
      u32x4 A0 = *(const u32x4*)(bt + i00), A1 = *(const u32x4*)(bt + i00 + 8);
      u32x4 B0 = *(const u32x4*)(bt + i01), B1 = *(const u32x4*)(bt + i01 + 8);
      u32x4 C0 = *(const u32x4*)(bt + i10), C1 = *(const u32x4*)(bt + i10 + 8);
      u32x4 D0 = *(const u32x4*)(bt + i11), D1 = *(const u32x4*)(bt + i11 + 8);

#define LERPU(a, b, c, d)                                                   \
  pack2(g00 * blo(a) + g01 * blo(b) + g10 * blo(c) + g11 * blo(d),          \
        g00 * bhi(a) + g01 * bhi(b) + g10 * bhi(c) + g11 * bhi(d))
      u32x4 v0, v1;
      v0[0] = LERPU(A0[0], B0[0], C0[0], D0[0]);
      v0[1] = LERPU(A0[1], B0[1], C0[1], D0[1]);
      v0[2] = LERPU(A0[2], B0[2], C0[2], D0[2]);
      v0[3] = LERPU(A0[3], B0[3], C0[3], D0[3]);
      v1[0] = LERPU(A1[0], B1[0], C1[0], D1[0]);
      v1[1] = LERPU(A1[1], B1[1], C1[1], D1[1]);
      v1[2] = LERPU(A1[2], B1[2], C1[2], D1[2]);
      v1[3] = LERPU(A1[3], B1[3], C1[3], D1[3]);
#undef LERPU

      __builtin_amdgcn_wave_barrier();
      *(u32x4*)&sA[wid][f][pt][grp * 16] = v0;
      *(u32x4*)&sA[wid][f][pt][grp * 16 + 8] = v1;
      __builtin_amdgcn_wave_barrier();   // same-wave LDS is in-order; fence compiler only

      short8 af0 = *(const short8*)&sA[wid][f][pt][grp * 8];
      short8 af1 = *(const short8*)&sA[wid][f][pt][32 + grp * 8];
      __builtin_amdgcn_wave_barrier();

      if (f == 0) {
        aA0 = __builtin_amdgcn_mfma_f32_16x16x32_bf16(af0, b00, aA0, 0, 0, 0);
        aA0 = __builtin_amdgcn_mfma_f32_16x16x32_bf16(af1, b01, aA0, 0, 0, 0);
        aA1 = __builtin_amdgcn_mfma_f32_16x16x32_bf16(af0, b10, aA1, 0, 0, 0);
        aA1 = __builtin_amdgcn_mfma_f32_16x16x32_bf16(af1, b11, aA1, 0, 0, 0);
        aA2 = __builtin_amdgcn_mfma_f32_16x16x32_bf16(af0, b20, aA2, 0, 0, 0);
        aA2 = __builtin_amdgcn_mfma_f32_16x16x32_bf16(af1, b21, aA2, 0, 0, 0);
        aA3 = __builtin_amdgcn_mfma_f32_16x16x32_bf16(af0, b30, aA3, 0, 0, 0);
        aA3 = __builtin_amdgcn_mfma_f32_16x16x32_bf16(af1, b31, aA3, 0, 0, 0);
      } else {
        aB0 = __builtin_amdgcn_mfma_f32_16x16x32_bf16(af0, b00, aB0, 0, 0, 0);
        aB0 = __builtin_amdgcn_mfma_f32_16x16x32_bf16(af1, b01, aB0, 0, 0, 0);
        aB1 = __builtin_amdgcn_mfma_f32_16x16x32_bf16(af0, b10, aB1, 0, 0, 0);
        aB1 = __builtin_amdgcn_mfma_f32_16x16x32_bf16(af1, b11, aB1, 0, 0, 0);
        aB2 = __builtin_amdgcn_mfma_f32_16x16x32_bf16(af0, b20, aB2, 0, 0, 0);
        aB2 = __builtin_amdgcn_mfma_f32_16x16x32_bf16(af1, b21, aB2, 0, 0, 0);
        aB3 = __builtin_amdgcn_mfma_f32_16x16x32_bf16(af0, b30, aB3, 0, 0, 0);
        aB3 = __builtin_amdgcn_mfma_f32_16x16x32_bf16(af1, b31, aB3, 0, 0, 0);
      }
    }
  }

  int ch = wid * 16 + pt;
  float bb = bias[ch];

  // phase 0: frag A
  red[wid][0][lane] = aA0;
  red[wid][1][lane] = aA1;
  red[wid][2][lane] = aA2;
  red[wid][3][lane] = aA3;
  __syncthreads();
  {
    f32x4 s = red[0][wid][lane];
    s = s + red[1][wid][lane];
    s = s + red[2][wid][lane];
    s = s + red[3][wid][lane];
#pragma unroll
    for (int r = 0; r < 4; ++r) {
      int p = p0 + grp * 4 + r;
      float v = s[r] + bb;
      if (MODE == 0) {
        v = (v >= 0.f) ? v : 0.1f * v;
        outb[(size_t)p * 64 + ch] = f2bf(v);
      } else {
        out32[(size_t)ch * P_ + p] = v + resid[(size_t)ch * P_ + p];
      }
    }
  }
  __syncthreads();
  // phase 1: frag B
  red[wid][0][lane] = aB0;
  red[wid][1][lane] = aB1;
  red[wid][2][lane] = aB2;
  red[wid][3][lane] = aB3;
  __syncthreads();
  {
    f32x4 s = red[0][wid][lane];
    s = s + red[1][wid][lane];
    s = s + red[2][wid][lane];
    s = s + red[3][wid][lane];
#pragma unroll
    for (int r = 0; r < 4; ++r) {
      int p = p0 + 16 + grp * 4 + r;
      float v = s[r] + bb;
      if (MODE == 0) {
        v = (v >= 0.f) ? v : 0.1f * v;
        outb[(size_t)p * 64 + ch] = f2bf(v);
      } else {
        out32[(size_t)ch * P_ + p] = v + resid[(size_t)ch * P_ + p];
      }
    }
  }
}

extern "C" void kernel_launch(void* const* d_in, const int* in_sizes, int n_in,
                              void* d_out, int out_size, void* d_ws, size_t ws_size,
                              hipStream_t stream) {
  const float* x      = (const float*)d_in[0];
  const float* w_off0 = (const float*)d_in[1];
  const float* b_off0 = (const float*)d_in[2];
  const float* w0     = (const float*)d_in[3];
  const float* b0     = (const float*)d_in[4];
  const float* w_off1 = (const float*)d_in[5];
  const float* b_off1 = (const float*)d_in[6];
  const float* w1     = (const float*)d_in[7];
  const float* b1     = (const float*)d_in[8];
  float* out = (float*)d_out;

  char* base = (char*)d_ws;
  unsigned short* x_clb = (unsigned short*)base;               // 2,064,384 B
  unsigned short* h_clb = (unsigned short*)(base + 2064384);   // 2,064,384 B
  float*          offt2 = (float*)(base + 4128768);            // 3,483,648 B
  unsigned short* wA0   = (unsigned short*)(base + 7612416);   // 221,184 B
  unsigned short* wA1   = (unsigned short*)(base + 7833600);
  unsigned short* wB0   = (unsigned short*)(base + 8054784);
  unsigned short* wB1   = (unsigned short*)(base + 8275968);   // end ~8.5 MB

  hipLaunchKernelGGL(k_prep_x, dim3(252), dim3(256), 0, stream, x, x_clb);
  hipLaunchKernelGGL(k_prep_w4, dim3(432, 4), dim3(256), 0, stream,
                     w_off0, w_off1, w0, w1, wA0, wA1, wB0, wB1);

  // layer 0
  hipLaunchKernelGGL(k_off4w, dim3(504), dim3(256), 0, stream, x_clb, wA0, b_off0, offt2);
  hipLaunchKernelGGL((k_samp4w<0>), dim3(504), dim3(256), 0, stream,
                     x_clb, offt2, wB0, b0, (const float*)nullptr, (float*)nullptr, h_clb);

  // layer 1
  hipLaunchKernelGGL(k_off4w, dim3(504), dim3(256), 0, stream, h_clb, wA1, b_off1, offt2);
  hipLaunchKernelGGL((k_samp4w<1>), dim3(504), dim3(256), 0, stream,
                     h_clb, offt2, wB1, b1, x, out, (unsigned short*)nullptr);
}